// Round 5
// baseline (253.085 us; speedup 1.0000x reference)
//
#include <hip/hip_runtime.h>
#include <hip/hip_bf16.h>
#include <math.h>

#define B_ 2
#define S_ 2048
#define D_ 1024
#define H_ 16
#define RANK_ 128
#define NC_ 16
#define DH_ 64
#define T_ (B_*S_)
#define NZ_ 2176          // z cols: 2048 z | 64 scores | 64 pad

typedef __attribute__((ext_vector_type(8))) __bf16 bf16x8;
typedef __attribute__((ext_vector_type(8))) unsigned short u16x8;
typedef __attribute__((ext_vector_type(4))) float f32x4;
typedef __attribute__((ext_vector_type(16))) float f32x16;

#if __has_builtin(__builtin_amdgcn_exp2f)
#define EXP2F(x) __builtin_amdgcn_exp2f(x)
#else
#define EXP2F(x) exp2f(x)
#endif

__device__ __forceinline__ unsigned short f2bu(float f) {
    __hip_bfloat16 h = __float2bfloat16(f);
    unsigned short u; __builtin_memcpy(&u, &h, 2); return u;
}
__device__ __forceinline__ float bu2f(unsigned short u) {
    __hip_bfloat16 h; __builtin_memcpy(&h, &u, 2); return __bfloat162float(h);
}

// async global->LDS 16B/lane; LDS dst = wave-uniform base (+ lane*16 implied)
__device__ __forceinline__ void gl_lds16(const unsigned short* g, unsigned short* l) {
    __builtin_amdgcn_global_load_lds(
        (const __attribute__((address_space(1))) void*)g,
        (__attribute__((address_space(3))) void*)l, 16, 0, 0);
}

// pack two f32 -> one u32 of 2x bf16 (lo -> [15:0])
__device__ __forceinline__ unsigned cvtpk_bf16(float lo, float hi) {
    unsigned r;
    asm("v_cvt_pk_bf16_f32 %0, %1, %2" : "=v"(r) : "v"(lo), "v"(hi));
    return r;
}
// swap hi 32 lanes of a with lo 32 lanes of b (both updated in place)
__device__ __forceinline__ void plswap(unsigned &a, unsigned &b) {
    asm("v_permlane32_swap_b32 %0, %1" : "+v"(a), "+v"(b));
}

__device__ __forceinline__ bool sniff_f32(const unsigned* __restrict__ p) {
    int votes = 0;
    #pragma unroll
    for (int i = 0; i < 64; i++) {
        unsigned e = (p[i] >> 23) & 0xFFu;
        votes += (e >= 0x60u && e <= 0x8Fu) ? 1 : 0;
    }
    return votes >= 32;
}

// ---------------------------------------------------------------------------
// merged input stage: blocks 0..511 = convert+transpose C; rest = flat converts
// ---------------------------------------------------------------------------
struct Cvt { const void* src[9]; unsigned short* dst[9]; const void* C; unsigned short* Ct; };

__global__ __launch_bounds__(256) void k_inputs(Cvt cv,
    const unsigned* __restrict__ probe)
{
    bool f32 = sniff_f32(probe);
    if (blockIdx.x < 512) {
        int bid = blockIdx.x;
        int d0 = (bid & 15) * 64, r0 = ((bid >> 4) & 1) * 64, n = bid >> 5;
        __shared__ unsigned short tile[64][65];
        for (int idx = threadIdx.x; idx < 4096; idx += 256) {
            int row = idx >> 6, col = idx & 63;
            size_t si = ((size_t)n*D_ + d0 + row)*RANK_ + r0 + col;
            tile[row][col] = f32 ? f2bu(((const float*)cv.C)[si])
                                 : ((const unsigned short*)cv.C)[si];
        }
        __syncthreads();
        for (int idx = threadIdx.x; idx < 4096; idx += 256) {
            int row = idx >> 6, col = idx & 63;
            cv.Ct[((size_t)(n*RANK_ + r0 + row))*D_ + d0 + col] = tile[col][row];
        }
        return;
    }
    const int offs[9] = {0, 4194304, 4210688, 4227072, 4243456,
                         4259840, 4390912, 4521984, 4653056};
    const int total = 5701632;
    int nconv = gridDim.x - 512;
    int stride = nconv * 256;
    for (int i = (blockIdx.x - 512) * 256 + threadIdx.x; i < total; i += stride) {
        int seg = 0;
        #pragma unroll
        for (int s = 1; s < 9; s++) seg += (i >= offs[s]) ? 1 : 0;
        int local = i - offs[seg];
        const void* sp = cv.src[seg];
        unsigned short v = 0;
        if (sp) v = f32 ? f2bu(((const float*)sp)[local]) : ((const unsigned short*)sp)[local];
        cv.dst[seg][local] = v;
    }
}

// ---------------------------------------------------------------------------
// MFMA NT GEMM, async-staged. Tile (MT*32)x128, BK=32.
// MODE: 0 = bf16 out; 2 = runtime-sniffed out dtype (fp32 vs bf16)
// ---------------------------------------------------------------------------
template<int MT, int MODE>
__global__ __launch_bounds__(256) void k_mfma_gemm(const unsigned short* __restrict__ A,
    const unsigned short* __restrict__ Bm, void* __restrict__ Cout,
    const unsigned* __restrict__ probe, int M, int N, int K)
{
    bool f32out = false;
    if (MODE == 2) f32out = sniff_f32(probe);
    __shared__ __align__(16) unsigned short As[MT*32*32];
    __shared__ __align__(16) unsigned short Bs[128*32];
    const int tid = threadIdx.x;
    const int wv = tid >> 6, lane = tid & 63;
    const int wm = (wv >> 1) * (MT*16), wn = (wv & 1) * 64;
    const int quad = lane >> 4, l16 = lane & 15;
    const int m0 = blockIdx.x * (MT*32), n0 = blockIdx.y * 128;

    const f32x4 z4 = {0.f, 0.f, 0.f, 0.f};
    f32x4 acc[MT][4];
    #pragma unroll
    for (int i = 0; i < MT; i++)
        #pragma unroll
        for (int j = 0; j < 4; j++) acc[i][j] = z4;

    for (int k0 = 0; k0 < K; k0 += 32) {
        __syncthreads();
        #pragma unroll
        for (int c = 0; c < MT/2; c++) {
            int idx = wv*64 + c*256 + lane;
            gl_lds16(A + (size_t)(m0 + (idx >> 2))*K + k0 + (idx & 3)*8,
                     &As[(wv*64 + c*256)*8]);
        }
        #pragma unroll
        for (int c = 0; c < 2; c++) {
            int idx = wv*64 + c*256 + lane;
            gl_lds16(Bm + (size_t)(n0 + (idx >> 2))*K + k0 + (idx & 3)*8,
                     &Bs[(wv*64 + c*256)*8]);
        }
        __syncthreads();
        bf16x8 af[MT], bfr[4];
        #pragma unroll
        for (int mt = 0; mt < MT; mt++) af[mt]  = *(const bf16x8*)&As[(wm + mt*16 + l16)*32 + quad*8];
        #pragma unroll
        for (int nt = 0; nt < 4; nt++) bfr[nt] = *(const bf16x8*)&Bs[(wn + nt*16 + l16)*32 + quad*8];
        #pragma unroll
        for (int mt = 0; mt < MT; mt++)
            #pragma unroll
            for (int nt = 0; nt < 4; nt++)
                acc[mt][nt] = __builtin_amdgcn_mfma_f32_16x16x32_bf16(af[mt], bfr[nt], acc[mt][nt], 0, 0, 0);
    }
    #pragma unroll
    for (int mt = 0; mt < MT; mt++)
        #pragma unroll
        for (int nt = 0; nt < 4; nt++) {
            int col = n0 + wn + nt*16 + l16;
            #pragma unroll
            for (int r = 0; r < 4; r++) {
                int rowg = m0 + wm + mt*16 + quad*4 + r;
                float v = acc[mt][nt][r];
                if (MODE == 2 && f32out) ((float*)Cout)[(size_t)rowg*N + col] = v;
                else  ((unsigned short*)Cout)[(size_t)rowg*N + col] = f2bu(v);
            }
        }
}

// ---------------------------------------------------------------------------
// merged Q|K + V^T GEMMs (K=128), one launch, 768 blocks.
// ---------------------------------------------------------------------------
__global__ __launch_bounds__(256) void k_qkv2(const unsigned short* __restrict__ h3,
    const unsigned short* __restrict__ wqkv, unsigned short* __restrict__ QKb,
    unsigned short* __restrict__ Vtg)
{
    __shared__ __align__(16) unsigned short As[128*32];
    __shared__ __align__(16) unsigned short Bs[128*32];
    const int tid = threadIdx.x;
    const int wv = tid >> 6, lane = tid & 63;
    const int wm = (wv >> 1) * 64, wn = (wv & 1) * 64;
    const int quad = lane >> 4, l16 = lane & 15;

    const bool vt = (blockIdx.x >= 512);
    int m0, n0;
    const unsigned short *A, *Bm;
    float scale = 1.f;
    if (!vt) {
        int id = blockIdx.x;
        m0 = (id & 31) * 128;                 // tokens
        n0 = (id >> 5) * 128;                 // Q|K cols (0..2047)
        int w = n0 >> 10;
        A  = h3 + (size_t)w * T_ * RANK_ + (size_t)m0 * RANK_;
        Bm = wqkv + (size_t)w * D_ * RANK_ + (size_t)(n0 & 1023) * RANK_;
        if (w == 0) scale = 0.125f * 1.44269504f;
    } else {
        int id = blockIdx.x - 512;
        m0 = (id & 7) * 128;                  // dv rows
        n0 = (id >> 3) * 128;                 // tokens
        A  = wqkv + (size_t)2 * D_ * RANK_ + (size_t)m0 * RANK_;
        Bm = h3 + (size_t)2 * T_ * RANK_ + (size_t)n0 * RANK_;
    }

    const f32x4 z4 = {0.f, 0.f, 0.f, 0.f};
    f32x4 acc[4][4];
    #pragma unroll
    for (int i = 0; i < 4; i++)
        #pragma unroll
        for (int j = 0; j < 4; j++) acc[i][j] = z4;

    for (int k0 = 0; k0 < RANK_; k0 += 32) {
        __syncthreads();
        #pragma unroll
        for (int c = 0; c < 2; c++) {
            int idx = wv*64 + c*256 + lane;
            gl_lds16(A  + (size_t)(idx >> 2)*RANK_ + k0 + (idx & 3)*8,
                     &As[(wv*64 + c*256)*8]);
            gl_lds16(Bm + (size_t)(idx >> 2)*RANK_ + k0 + (idx & 3)*8,
                     &Bs[(wv*64 + c*256)*8]);
        }
        __syncthreads();
        bf16x8 af[4], bfr[4];
        #pragma unroll
        for (int mt = 0; mt < 4; mt++) af[mt]  = *(const bf16x8*)&As[(wm + mt*16 + l16)*32 + quad*8];
        #pragma unroll
        for (int nt = 0; nt < 4; nt++) bfr[nt] = *(const bf16x8*)&Bs[(wn + nt*16 + l16)*32 + quad*8];
        #pragma unroll
        for (int mt = 0; mt < 4; mt++)
            #pragma unroll
            for (int nt = 0; nt < 4; nt++)
                acc[mt][nt] = __builtin_amdgcn_mfma_f32_16x16x32_bf16(af[mt], bfr[nt], acc[mt][nt], 0, 0, 0);
    }
    #pragma unroll
    for (int mt = 0; mt < 4; mt++)
        #pragma unroll
        for (int nt = 0; nt < 4; nt++) {
            #pragma unroll
            for (int r = 0; r < 4; r++) {
                int rowg = m0 + wm + mt*16 + quad*4 + r;
                int col  = n0 + wn + nt*16 + l16;
                float v = acc[mt][nt][r] * scale;
                if (!vt) {
                    QKb[(size_t)(col >> 10)*T_*D_ + (size_t)rowg*D_ + (col & 1023)]
                        = f2bu(v);
                } else {
                    size_t vrow = (size_t)((col >> 11)*H_ + (rowg >> 6))*64 + (rowg & 63);
                    Vtg[vrow*S_ + (col & 2047)] = f2bu(v);
                }
            }
        }
}

// ---------------------------------------------------------------------------
// hreduce + router softmax (scores in z cols 2048..2095)
// ---------------------------------------------------------------------------
__global__ __launch_bounds__(256) void k_hreduce(const unsigned short* __restrict__ z,
    unsigned short* __restrict__ h)
{
    int t0 = blockIdx.x * 2;
    int tg = threadIdx.x >> 7, r = threadIdx.x & 127;
    int t = t0 + tg;
    __shared__ float sc[2][48];
    __shared__ float wl[2][3][16];
    if (threadIdx.x < 96) {
        int tk = threadIdx.x / 48, j = threadIdx.x % 48;
        sc[tk][j] = bu2f(z[(size_t)(t0 + tk)*NZ_ + 2048 + j]);
    }
    __syncthreads();
    if (threadIdx.x < 6) {
        int tk = threadIdx.x / 3, w = threadIdx.x % 3;
        float m = -INFINITY;
        for (int n = 0; n < 16; n++) m = fmaxf(m, sc[tk][w*16 + n]);
        float s = 0.f, e[16];
        for (int n = 0; n < 16; n++) { e[n] = __expf(sc[tk][w*16 + n] - m); s += e[n]; }
        float inv = 1.f / s;
        for (int n = 0; n < 16; n++) wl[tk][w][n] = e[n] * inv;
    }
    __syncthreads();
    const unsigned short* zr = z + (size_t)t * NZ_;
    float acc[3] = {0.f, 0.f, 0.f};
    #pragma unroll
    for (int n = 0; n < NC_; n++) {
        float zv = bu2f(zr[n*RANK_ + r]);
        #pragma unroll
        for (int w = 0; w < 3; w++) acc[w] += wl[tg][w][n] * zv;
    }
    #pragma unroll
    for (int w = 0; w < 3; w++) h[((size_t)w*T_ + t)*RANK_ + r] = f2bu(acc[w]);
}

// ---------------------------------------------------------------------------
// MFMA causal flash attention — KEY-SPLIT uniform-quota blocks.
//   - Proven inner loop (32x32x16 swapped QK^T, lane-local exp2 softmax,
//     in-register P->bf16 via cvt_pk + permlane32_swap, 2-buf DMA dbuf,
//     one barrier/iter) UNCHANGED.
//   - Each block now handles a (q-tile, key-subrange): qt in [12,15] split
//     4-way, [8,11] 3-way, [4,7] 2-way, [0,3] unsplit -> 40 blocks/(b,h),
//     ALL with 2..8 key-tile visits. 1280 blocks, 5/CU (5x32 KiB = 160 KiB
//     LDS): sustained 4-5-way block concurrency on every CU, no temporal
//     degeneracy (R4 lesson: sum-balance isn't enough; no block may be long).
//   - Blocks write UNNORMALIZED f32 partials (O_jj, l_jj); fixed-max exp2
//     makes merging a pure sum (k_merge below).
//   - i%8 == gr%8 -> XCD-clustered K/V (R4's FETCH win preserved).
//   - T5: s_setprio(1) around MFMA clusters.
// ---------------------------------------------------------------------------
__global__ __launch_bounds__(256, 5) void k_flash_mfma(const unsigned short* __restrict__ Qm,
    const unsigned short* __restrict__ Km, const unsigned short* __restrict__ Vtg,
    float* __restrict__ Op, float* __restrict__ lp)
{
    const int i = blockIdx.x;                  // 0..1279
    const int gr = i & 31, u = i >> 5;         // gr = (b,h); u = 0..39
    int qt, jj;
    if (u < 16)      { qt = 15 - (u >> 2);          jj = u & 3; }
    else if (u < 28) { int v = u - 16; qt = 11 - v/3; jj = v - (11 - qt)*3; }
    else if (u < 36) { int v = u - 28; qt = 7 - (v >> 1); jj = v & 1; }
    else             { qt = 3 - (u - 36);           jj = 0; }
    const int hh = gr & 15, b = gr >> 4;
    const int ns = (2*qt + 9) >> 3;            // splits for this qt
    const int nall = 2*(qt + 1);
    const int q_ = nall / ns, rem = nall - q_*ns;
    const int n = q_ + (jj < rem ? 1 : 0);     // local key-tile count (2..8)
    const int kt0 = jj*q_ + (jj < rem ? jj : rem);

    __shared__ __align__(16) unsigned short Ks[2][64*64];  // [key][dh], xor-swz
    __shared__ __align__(16) unsigned short Vs[2][64*64];  // [dh][key], xor-swz
    const int tid = threadIdx.x;
    const int w = tid >> 6, lane = tid & 63;
    const int l32 = lane & 31, hi = lane >> 5;
    const size_t base  = ((size_t)b * S_) * D_ + (size_t)hh * DH_;
    const size_t vbase = (size_t)((b*H_ + hh) * 64) * S_;
    const int tokg = qt*128 + w*32 + l32;      // this lane's token (B-operand col)

    // Q fragments: B-operand, 4 dh-chunks of 16 (lane supplies k = hi*8..+8)
    bf16x8 aq[4];
    #pragma unroll
    for (int ks = 0; ks < 4; ks++)
        aq[ks] = *(const bf16x8*)(Qm + base + (size_t)tokg*D_ + ks*16 + hi*8);

    f32x16 oacc[2];
    #pragma unroll
    for (int db = 0; db < 2; db++)
        #pragma unroll
        for (int ii = 0; ii < 16; ii++) oacc[db][ii] = 0.f;
    float lsum = 0.f;

    // prefetch first tile -> buf 0
    #pragma unroll
    for (int c = 0; c < 2; c++) {
        int idx = c*256 + tid;
        int row = idx >> 3, j = (idx & 7) ^ (row & 7);
        gl_lds16(Km + base + (size_t)(kt0*64 + row)*D_ + j*8,
                 &Ks[0][(c*256 + (w<<6))*8]);
    }
    #pragma unroll
    for (int c = 0; c < 2; c++) {
        int idx = c*256 + tid;
        int row = idx >> 3, j = (idx & 7) ^ (row & 7);
        gl_lds16(Vtg + vbase + (size_t)row*S_ + kt0*64 + j*8,
                 &Vs[0][(c*256 + (w<<6))*8]);
    }

    for (int t = 0; t < n; t++) {
        const int kt = kt0 + t;
        const int cur = t & 1;
        __syncthreads();                       // drains tile-t DMA (full-iter flight)

        if (t + 1 < n) {                       // prefetch next tile -> other buffers
            #pragma unroll
            for (int c = 0; c < 2; c++) {
                int idx = c*256 + tid;
                int row = idx >> 3, j = (idx & 7) ^ (row & 7);
                gl_lds16(Km + base + (size_t)((kt+1)*64 + row)*D_ + j*8,
                         &Ks[1-cur][(c*256 + (w<<6))*8]);
            }
            #pragma unroll
            for (int c = 0; c < 2; c++) {
                int idx = c*256 + tid;
                int row = idx >> 3, j = (idx & 7) ^ (row & 7);
                gl_lds16(Vtg + vbase + (size_t)row*S_ + (kt+1)*64 + j*8,
                         &Vs[1-cur][(c*256 + (w<<6))*8]);
            }
        }

        // S^T = K Q^T (log2 domain): sacc[kb] = 32 keys x 32 toks, tok = lane col
        f32x16 sacc[2];
        #pragma unroll
        for (int kb = 0; kb < 2; kb++)
            #pragma unroll
            for (int ii = 0; ii < 16; ii++) sacc[kb][ii] = 0.f;
        __builtin_amdgcn_s_setprio(1);
        #pragma unroll
        for (int ks = 0; ks < 4; ks++)
            #pragma unroll
            for (int kb = 0; kb < 2; kb++) {
                int row = kb*32 + l32;
                int c = (ks*2 + hi) ^ (row & 7);
                bf16x8 ak = *(const bf16x8*)&Ks[cur][row*64 + c*8];
                sacc[kb] = __builtin_amdgcn_mfma_f32_32x32x16_bf16(ak, aq[ks], sacc[kb], 0, 0, 0);
            }
        __builtin_amdgcn_s_setprio(0);

        if (kt >= 2*qt) {                      // diagonal tiles: causal mask
            #pragma unroll
            for (int kb = 0; kb < 2; kb++)
                #pragma unroll
                for (int r = 0; r < 16; r++) {
                    int keyg = kt*64 + kb*32 + (r&3) + 8*(r>>2) + 4*hi;
                    if (keyg > tokg) sacc[kb][r] = -INFINITY;
                }
        }

        // exp2 + in-register pack to PV A-fragments (cvt_pk + permlane32_swap)
        bf16x8 pa[4];
        #pragma unroll
        for (int kb = 0; kb < 2; kb++) {
            float pv[16];
            #pragma unroll
            for (int r = 0; r < 16; r++) {
                pv[r] = EXP2F(sacc[kb][r]);
                lsum += pv[r];
            }
            unsigned wd[8];
            #pragma unroll
            for (int j = 0; j < 8; j++) wd[j] = cvtpk_bf16(pv[2*j], pv[2*j+1]);
            plswap(wd[0], wd[2]); plswap(wd[1], wd[3]);
            plswap(wd[4], wd[6]); plswap(wd[5], wd[7]);
            union { unsigned u[4]; bf16x8 v; } u0, u1;
            u0.u[0]=wd[0]; u0.u[1]=wd[1]; u0.u[2]=wd[2]; u0.u[3]=wd[3];
            u1.u[0]=wd[4]; u1.u[1]=wd[5]; u1.u[2]=wd[6]; u1.u[3]=wd[7];
            pa[2*kb]   = u0.v;
            pa[2*kb+1] = u1.v;
        }

        // O += P V  (V^T staged as [dh][key]; B-operand rows = dh)
        __builtin_amdgcn_s_setprio(1);
        #pragma unroll
        for (int ks = 0; ks < 4; ks++)
            #pragma unroll
            for (int db = 0; db < 2; db++) {
                int row = db*32 + l32;
                int c = (ks*2 + hi) ^ (row & 7);
                bf16x8 bv = *(const bf16x8*)&Vs[cur][row*64 + c*8];
                oacc[db] = __builtin_amdgcn_mfma_f32_32x32x16_bf16(pa[ks], bv, oacc[db], 0, 0, 0);
            }
        __builtin_amdgcn_s_setprio(0);
    }

    // write UNNORMALIZED partials: lane l32 holds l for its token after reduce
    float l = lsum + __shfl_xor(lsum, 32);
    if (hi == 0)
        lp[((size_t)(jj*B_ + b)*H_ + hh)*S_ + qt*128 + w*32 + l32] = l;
    float* Ob = Op + (size_t)jj * T_ * D_;
    #pragma unroll
    for (int r = 0; r < 16; r++) {
        int crow = (r&3) + 8*(r>>2) + 4*hi;
        size_t rowo = base + (size_t)(qt*128 + w*32 + crow)*D_;
        #pragma unroll
        for (int db = 0; db < 2; db++)
            Ob[rowo + db*32 + l32] = oacc[db][r];
    }
}

// ---------------------------------------------------------------------------
// merge key-split partials: attnb = (sum_jj O_jj) / (sum_jj l_jj), bf16 out
// ---------------------------------------------------------------------------
__global__ __launch_bounds__(256) void k_merge(const float* __restrict__ Op,
    const float* __restrict__ lp, unsigned short* __restrict__ attnb)
{
    const size_t i = ((size_t)blockIdx.x * 256 + threadIdx.x) * 8;
    const int tf = (int)(i >> 10);             // b*S + tok   (D_ = 1024)
    const int d0 = (int)(i & 1023);
    const int h = d0 >> 6;
    const int b = tf >> 11, tok = tf & (S_-1); // S_ = 2048
    const int qt = tok >> 7;
    const int ns = (2*qt + 9) >> 3;
    float a[8] = {0,0,0,0,0,0,0,0};
    float l = 0.f;
    for (int jj = 0; jj < ns; jj++) {
        const float* O = Op + (size_t)jj * T_ * D_;
        f32x4 a0 = *(const f32x4*)(O + i);
        f32x4 a1 = *(const f32x4*)(O + i + 4);
        #pragma unroll
        for (int j = 0; j < 4; j++) { a[j] += a0[j]; a[4+j] += a1[j]; }
        l += lp[((size_t)(jj*B_ + b)*H_ + h)*S_ + tok];
    }
    float inv = 1.f / l;
    u16x8 o8;
    #pragma unroll
    for (int j = 0; j < 8; j++) o8[j] = f2bu(a[j] * inv);
    *(u16x8*)(attnb + i) = o8;
}

// ---------------------------------------------------------------------------
// launch
// ---------------------------------------------------------------------------
extern "C" void kernel_launch(void* const* d_in, const int* in_sizes, int n_in,
                              void* d_out, int out_size, void* d_ws, size_t ws_size,
                              hipStream_t stream)
{
    const unsigned* probe = (const unsigned*)d_in[0];

    unsigned short* u = (unsigned short*)d_ws;
    unsigned short* xc   = u;               size_t o = (size_t)T_*D_;
    unsigned short* wqkv = u + o;           o += (size_t)3*D_*RANK_;
    unsigned short* wOc  = u + o;           o += (size_t)D_*D_;
    unsigned short* Ct   = u + o;           o += (size_t)NZ_*D_;      // 2048 Ct | 64 Rpad | 64 pad
    unsigned short* h3   = u + o;           o += (size_t)3*T_*RANK_;
    unsigned short* QKb  = u + o;           o += (size_t)2*T_*D_;     // Q | K
    unsigned short* Vtg  = u + o;           o += (size_t)T_*D_;
    unsigned short* z    = u + o;           o += (size_t)T_*NZ_;
    unsigned short* attnb= u + o;           o += (size_t)T_*D_;
    float* Opart = (float*)(u + o);         o += (size_t)8*T_*D_;     // 4 x T*D f32
    float* lpart = (float*)(u + o);         o += (size_t)8*B_*H_*S_;  // 4 x B*H*S f32

    unsigned short* Rp = Ct + (size_t)2048*D_;
    unsigned short* Qb = QKb;
    unsigned short* Kb = QKb + (size_t)T_*D_;

    Cvt cv;
    cv.src[0] = d_in[0]; cv.dst[0] = xc;
    cv.src[1] = d_in[3]; cv.dst[1] = Rp;
    cv.src[2] = d_in[4]; cv.dst[2] = Rp + 16384;
    cv.src[3] = d_in[5]; cv.dst[3] = Rp + 32768;
    cv.src[4] = nullptr; cv.dst[4] = Rp + 49152;
    cv.src[5] = d_in[6]; cv.dst[5] = wqkv;
    cv.src[6] = d_in[7]; cv.dst[6] = wqkv + 131072;
    cv.src[7] = d_in[8]; cv.dst[7] = wqkv + 262144;
    cv.src[8] = d_in[9]; cv.dst[8] = wOc;
    cv.C = d_in[2]; cv.Ct = Ct;
    k_inputs<<<512 + 2048, 256, 0, stream>>>(cv, probe);

    k_mfma_gemm<4,0><<<dim3(T_/128, NZ_/128), 256, 0, stream>>>(
        xc, Ct, z, nullptr, T_, NZ_, D_);

    k_hreduce<<<T_/2, 256, 0, stream>>>(z, h3);

    k_qkv2<<<768, 256, 0, stream>>>(h3, wqkv, QKb, Vtg);

    k_flash_mfma<<<dim3(1280), 256, 0, stream>>>(Qb, Kb, Vtg, Opart, lpart);

    k_merge<<<dim3(T_*D_/2048), 256, 0, stream>>>(Opart, lpart, attnb);

    k_mfma_gemm<2,2><<<dim3(T_/64, D_/128), 256, 0, stream>>>(
        attnb, wOc, d_out, probe, T_, D_, D_);
}

// Round 6
// 250.777 us; speedup vs baseline: 1.0092x; 1.0092x over previous
//
#include <hip/hip_runtime.h>
#include <hip/hip_bf16.h>
#include <math.h>

#define B_ 2
#define S_ 2048
#define D_ 1024
#define H_ 16
#define RANK_ 128
#define NC_ 16
#define DH_ 64
#define T_ (B_*S_)
#define NZ_ 2176          // z cols: 2048 z | 64 scores | 64 pad

typedef __attribute__((ext_vector_type(8))) __bf16 bf16x8;
typedef __attribute__((ext_vector_type(8))) unsigned short u16x8;
typedef __attribute__((ext_vector_type(4))) float f32x4;
typedef __attribute__((ext_vector_type(16))) float f32x16;

#if __has_builtin(__builtin_amdgcn_exp2f)
#define EXP2F(x) __builtin_amdgcn_exp2f(x)
#else
#define EXP2F(x) exp2f(x)
#endif

__device__ __forceinline__ unsigned short f2bu(float f) {
    __hip_bfloat16 h = __float2bfloat16(f);
    unsigned short u; __builtin_memcpy(&u, &h, 2); return u;
}
__device__ __forceinline__ float bu2f(unsigned short u) {
    __hip_bfloat16 h; __builtin_memcpy(&h, &u, 2); return __bfloat162float(h);
}

// async global->LDS 16B/lane; LDS dst = wave-uniform base (+ lane*16 implied)
__device__ __forceinline__ void gl_lds16(const unsigned short* g, unsigned short* l) {
    __builtin_amdgcn_global_load_lds(
        (const __attribute__((address_space(1))) void*)g,
        (__attribute__((address_space(3))) void*)l, 16, 0, 0);
}

// pack two f32 -> one u32 of 2x bf16 (lo -> [15:0])
__device__ __forceinline__ unsigned cvtpk_bf16(float lo, float hi) {
    unsigned r;
    asm("v_cvt_pk_bf16_f32 %0, %1, %2" : "=v"(r) : "v"(lo), "v"(hi));
    return r;
}
// swap hi 32 lanes of a with lo 32 lanes of b (both updated in place)
__device__ __forceinline__ void plswap(unsigned &a, unsigned &b) {
    asm("v_permlane32_swap_b32 %0, %1" : "+v"(a), "+v"(b));
}

__device__ __forceinline__ bool sniff_f32(const unsigned* __restrict__ p) {
    int votes = 0;
    #pragma unroll
    for (int i = 0; i < 64; i++) {
        unsigned e = (p[i] >> 23) & 0xFFu;
        votes += (e >= 0x60u && e <= 0x8Fu) ? 1 : 0;
    }
    return votes >= 32;
}

// ---------------------------------------------------------------------------
// merged input stage: blocks 0..511 = convert+transpose C; rest = flat converts
// ---------------------------------------------------------------------------
struct Cvt { const void* src[9]; unsigned short* dst[9]; const void* C; unsigned short* Ct; };

__global__ __launch_bounds__(256) void k_inputs(Cvt cv,
    const unsigned* __restrict__ probe)
{
    bool f32 = sniff_f32(probe);
    if (blockIdx.x < 512) {
        int bid = blockIdx.x;
        int d0 = (bid & 15) * 64, r0 = ((bid >> 4) & 1) * 64, n = bid >> 5;
        __shared__ unsigned short tile[64][65];
        for (int idx = threadIdx.x; idx < 4096; idx += 256) {
            int row = idx >> 6, col = idx & 63;
            size_t si = ((size_t)n*D_ + d0 + row)*RANK_ + r0 + col;
            tile[row][col] = f32 ? f2bu(((const float*)cv.C)[si])
                                 : ((const unsigned short*)cv.C)[si];
        }
        __syncthreads();
        for (int idx = threadIdx.x; idx < 4096; idx += 256) {
            int row = idx >> 6, col = idx & 63;
            cv.Ct[((size_t)(n*RANK_ + r0 + row))*D_ + d0 + col] = tile[col][row];
        }
        return;
    }
    const int offs[9] = {0, 4194304, 4210688, 4227072, 4243456,
                         4259840, 4390912, 4521984, 4653056};
    const int total = 5701632;
    int nconv = gridDim.x - 512;
    int stride = nconv * 256;
    for (int i = (blockIdx.x - 512) * 256 + threadIdx.x; i < total; i += stride) {
        int seg = 0;
        #pragma unroll
        for (int s = 1; s < 9; s++) seg += (i >= offs[s]) ? 1 : 0;
        int local = i - offs[seg];
        const void* sp = cv.src[seg];
        unsigned short v = 0;
        if (sp) v = f32 ? f2bu(((const float*)sp)[local]) : ((const unsigned short*)sp)[local];
        cv.dst[seg][local] = v;
    }
}

// ---------------------------------------------------------------------------
// MFMA NT GEMM, async-staged. Tile (MT*32)x128, BK=32.
// MODE: 0 = bf16 out; 2 = runtime-sniffed out dtype (fp32 vs bf16)
// ---------------------------------------------------------------------------
template<int MT, int MODE>
__global__ __launch_bounds__(256) void k_mfma_gemm(const unsigned short* __restrict__ A,
    const unsigned short* __restrict__ Bm, void* __restrict__ Cout,
    const unsigned* __restrict__ probe, int M, int N, int K)
{
    bool f32out = false;
    if (MODE == 2) f32out = sniff_f32(probe);
    __shared__ __align__(16) unsigned short As[MT*32*32];
    __shared__ __align__(16) unsigned short Bs[128*32];
    const int tid = threadIdx.x;
    const int wv = tid >> 6, lane = tid & 63;
    const int wm = (wv >> 1) * (MT*16), wn = (wv & 1) * 64;
    const int quad = lane >> 4, l16 = lane & 15;
    const int m0 = blockIdx.x * (MT*32), n0 = blockIdx.y * 128;

    const f32x4 z4 = {0.f, 0.f, 0.f, 0.f};
    f32x4 acc[MT][4];
    #pragma unroll
    for (int i = 0; i < MT; i++)
        #pragma unroll
        for (int j = 0; j < 4; j++) acc[i][j] = z4;

    for (int k0 = 0; k0 < K; k0 += 32) {
        __syncthreads();
        #pragma unroll
        for (int c = 0; c < MT/2; c++) {
            int idx = wv*64 + c*256 + lane;
            gl_lds16(A + (size_t)(m0 + (idx >> 2))*K + k0 + (idx & 3)*8,
                     &As[(wv*64 + c*256)*8]);
        }
        #pragma unroll
        for (int c = 0; c < 2; c++) {
            int idx = wv*64 + c*256 + lane;
            gl_lds16(Bm + (size_t)(n0 + (idx >> 2))*K + k0 + (idx & 3)*8,
                     &Bs[(wv*64 + c*256)*8]);
        }
        __syncthreads();
        bf16x8 af[MT], bfr[4];
        #pragma unroll
        for (int mt = 0; mt < MT; mt++) af[mt]  = *(const bf16x8*)&As[(wm + mt*16 + l16)*32 + quad*8];
        #pragma unroll
        for (int nt = 0; nt < 4; nt++) bfr[nt] = *(const bf16x8*)&Bs[(wn + nt*16 + l16)*32 + quad*8];
        #pragma unroll
        for (int mt = 0; mt < MT; mt++)
            #pragma unroll
            for (int nt = 0; nt < 4; nt++)
                acc[mt][nt] = __builtin_amdgcn_mfma_f32_16x16x32_bf16(af[mt], bfr[nt], acc[mt][nt], 0, 0, 0);
    }
    #pragma unroll
    for (int mt = 0; mt < MT; mt++)
        #pragma unroll
        for (int nt = 0; nt < 4; nt++) {
            int col = n0 + wn + nt*16 + l16;
            #pragma unroll
            for (int r = 0; r < 4; r++) {
                int rowg = m0 + wm + mt*16 + quad*4 + r;
                float v = acc[mt][nt][r];
                if (MODE == 2 && f32out) ((float*)Cout)[(size_t)rowg*N + col] = v;
                else  ((unsigned short*)Cout)[(size_t)rowg*N + col] = f2bu(v);
            }
        }
}

// ---------------------------------------------------------------------------
// merged Q|K + V^T GEMMs (K=128), one launch, 768 blocks.
// ---------------------------------------------------------------------------
__global__ __launch_bounds__(256) void k_qkv2(const unsigned short* __restrict__ h3,
    const unsigned short* __restrict__ wqkv, unsigned short* __restrict__ QKb,
    unsigned short* __restrict__ Vtg)
{
    __shared__ __align__(16) unsigned short As[128*32];
    __shared__ __align__(16) unsigned short Bs[128*32];
    const int tid = threadIdx.x;
    const int wv = tid >> 6, lane = tid & 63;
    const int wm = (wv >> 1) * 64, wn = (wv & 1) * 64;
    const int quad = lane >> 4, l16 = lane & 15;

    const bool vt = (blockIdx.x >= 512);
    int m0, n0;
    const unsigned short *A, *Bm;
    float scale = 1.f;
    if (!vt) {
        int id = blockIdx.x;
        m0 = (id & 31) * 128;                 // tokens
        n0 = (id >> 5) * 128;                 // Q|K cols (0..2047)
        int w = n0 >> 10;
        A  = h3 + (size_t)w * T_ * RANK_ + (size_t)m0 * RANK_;
        Bm = wqkv + (size_t)w * D_ * RANK_ + (size_t)(n0 & 1023) * RANK_;
        if (w == 0) scale = 0.125f * 1.44269504f;
    } else {
        int id = blockIdx.x - 512;
        m0 = (id & 7) * 128;                  // dv rows
        n0 = (id >> 3) * 128;                 // tokens
        A  = wqkv + (size_t)2 * D_ * RANK_ + (size_t)m0 * RANK_;
        Bm = h3 + (size_t)2 * T_ * RANK_ + (size_t)n0 * RANK_;
    }

    const f32x4 z4 = {0.f, 0.f, 0.f, 0.f};
    f32x4 acc[4][4];
    #pragma unroll
    for (int i = 0; i < 4; i++)
        #pragma unroll
        for (int j = 0; j < 4; j++) acc[i][j] = z4;

    for (int k0 = 0; k0 < RANK_; k0 += 32) {
        __syncthreads();
        #pragma unroll
        for (int c = 0; c < 2; c++) {
            int idx = wv*64 + c*256 + lane;
            gl_lds16(A  + (size_t)(idx >> 2)*RANK_ + k0 + (idx & 3)*8,
                     &As[(wv*64 + c*256)*8]);
            gl_lds16(Bm + (size_t)(idx >> 2)*RANK_ + k0 + (idx & 3)*8,
                     &Bs[(wv*64 + c*256)*8]);
        }
        __syncthreads();
        bf16x8 af[4], bfr[4];
        #pragma unroll
        for (int mt = 0; mt < 4; mt++) af[mt]  = *(const bf16x8*)&As[(wm + mt*16 + l16)*32 + quad*8];
        #pragma unroll
        for (int nt = 0; nt < 4; nt++) bfr[nt] = *(const bf16x8*)&Bs[(wn + nt*16 + l16)*32 + quad*8];
        #pragma unroll
        for (int mt = 0; mt < 4; mt++)
            #pragma unroll
            for (int nt = 0; nt < 4; nt++)
                acc[mt][nt] = __builtin_amdgcn_mfma_f32_16x16x32_bf16(af[mt], bfr[nt], acc[mt][nt], 0, 0, 0);
    }
    #pragma unroll
    for (int mt = 0; mt < 4; mt++)
        #pragma unroll
        for (int nt = 0; nt < 4; nt++) {
            #pragma unroll
            for (int r = 0; r < 4; r++) {
                int rowg = m0 + wm + mt*16 + quad*4 + r;
                int col  = n0 + wn + nt*16 + l16;
                float v = acc[mt][nt][r] * scale;
                if (!vt) {
                    QKb[(size_t)(col >> 10)*T_*D_ + (size_t)rowg*D_ + (col & 1023)]
                        = f2bu(v);
                } else {
                    size_t vrow = (size_t)((col >> 11)*H_ + (rowg >> 6))*64 + (rowg & 63);
                    Vtg[vrow*S_ + (col & 2047)] = f2bu(v);
                }
            }
        }
}

// ---------------------------------------------------------------------------
// hreduce + router softmax (scores in z cols 2048..2095)
// ---------------------------------------------------------------------------
__global__ __launch_bounds__(256) void k_hreduce(const unsigned short* __restrict__ z,
    unsigned short* __restrict__ h)
{
    int t0 = blockIdx.x * 2;
    int tg = threadIdx.x >> 7, r = threadIdx.x & 127;
    int t = t0 + tg;
    __shared__ float sc[2][48];
    __shared__ float wl[2][3][16];
    if (threadIdx.x < 96) {
        int tk = threadIdx.x / 48, j = threadIdx.x % 48;
        sc[tk][j] = bu2f(z[(size_t)(t0 + tk)*NZ_ + 2048 + j]);
    }
    __syncthreads();
    if (threadIdx.x < 6) {
        int tk = threadIdx.x / 3, w = threadIdx.x % 3;
        float m = -INFINITY;
        for (int n = 0; n < 16; n++) m = fmaxf(m, sc[tk][w*16 + n]);
        float s = 0.f, e[16];
        for (int n = 0; n < 16; n++) { e[n] = __expf(sc[tk][w*16 + n] - m); s += e[n]; }
        float inv = 1.f / s;
        for (int n = 0; n < 16; n++) wl[tk][w][n] = e[n] * inv;
    }
    __syncthreads();
    const unsigned short* zr = z + (size_t)t * NZ_;
    float acc[3] = {0.f, 0.f, 0.f};
    #pragma unroll
    for (int n = 0; n < NC_; n++) {
        float zv = bu2f(zr[n*RANK_ + r]);
        #pragma unroll
        for (int w = 0; w < 3; w++) acc[w] += wl[tg][w][n] * zv;
    }
    #pragma unroll
    for (int w = 0; w < 3; w++) h[((size_t)w*T_ + t)*RANK_ + r] = f2bu(acc[w]);
}

// ---------------------------------------------------------------------------
// MFMA causal flash attention — 2-wave blocks, 64 tok/wave (MFMA:DS = 2:1).
//   - R4's balanced complementary mapping and inner-loop structure kept:
//     512 blocks; block i and i+256 share a CU with qt = 15-ts / ts ->
//     constant 34 key-tile visits per CU; i%8 == gr%8 -> XCD-clustered K/V.
//   - NEW: 128 threads (2 waves), each wave owns 64 tokens (2 q-subtiles).
//     Every K/V ds_read_b128 now feeds TWO MFMAs -> per-visit DS reads
//     halve (R4 ran at the SUM of pipe busy times; DS was the biggest term).
//   - 32x32x16 swapped QK^T (S^T, token = lane col); lane-local exp2
//     softmax; in-register P->bf16 via v_cvt_pk_bf16_f32 + permlane32_swap.
//   - K,V double-buffered via async DMA prefetched one full iteration ahead,
//     ONE barrier/iter. LDS 32 KiB. No setprio (m190/R5: hurts lockstep).
// ---------------------------------------------------------------------------
__global__ __launch_bounds__(128) void k_flash_mfma(const unsigned short* __restrict__ Qm,
    const unsigned short* __restrict__ Km, const unsigned short* __restrict__ Vtg,
    unsigned short* __restrict__ Om)
{
    const int i = blockIdx.x;                  // 0..511
    const int half = i >> 8, r_ = i & 255;
    const int gr = r_ & 31, ts = r_ >> 5;      // gr = (b,h) group; ts = 0..7
    const int qt = half ? ts : (15 - ts);      // complementary halves
    const int hh = gr & 15, b = gr >> 4;

    __shared__ __align__(16) unsigned short Ks[2][64*64];  // [key][dh], xor-swz
    __shared__ __align__(16) unsigned short Vs[2][64*64];  // [dh][key], xor-swz
    const int tid = threadIdx.x;
    const int w = tid >> 6, lane = tid & 63;
    const int l32 = lane & 31, hi = lane >> 5;
    const size_t base  = ((size_t)b * S_) * D_ + (size_t)hh * DH_;
    const size_t vbase = (size_t)((b*H_ + hh) * 64) * S_;
    const int tok0 = qt*128 + w*64;            // wave's first token

    // Q fragments: B-operand, col = l32 = token, k-slice = hi*8 (2 q-subtiles)
    bf16x8 aq[2][4];
    #pragma unroll
    for (int tq = 0; tq < 2; tq++)
        #pragma unroll
        for (int ks = 0; ks < 4; ks++)
            aq[tq][ks] = *(const bf16x8*)(Qm + base +
                (size_t)(tok0 + tq*32 + l32)*D_ + ks*16 + hi*8);

    f32x16 oacc[2][2];
    #pragma unroll
    for (int tq = 0; tq < 2; tq++)
        #pragma unroll
        for (int db = 0; db < 2; db++)
            #pragma unroll
            for (int ii = 0; ii < 16; ii++) oacc[tq][db][ii] = 0.f;
    float ls[2][4];
    #pragma unroll
    for (int tq = 0; tq < 2; tq++)
        #pragma unroll
        for (int j = 0; j < 4; j++) ls[tq][j] = 0.f;

    const int nkt = 2*(qt + 1);                // 64-key tiles up to the diagonal

    // prefetch tile 0 -> buf 0 (64 rows x 8 chunks = 512; 4 chunks/thread)
    #pragma unroll
    for (int c = 0; c < 4; c++) {
        int idx = c*128 + tid;
        int row = idx >> 3, j = (idx & 7) ^ (row & 7);
        gl_lds16(Km + base + (size_t)row*D_ + j*8, &Ks[0][(c*128 + (w<<6))*8]);
    }
    #pragma unroll
    for (int c = 0; c < 4; c++) {
        int idx = c*128 + tid;
        int row = idx >> 3, j = (idx & 7) ^ (row & 7);
        gl_lds16(Vtg + vbase + (size_t)row*S_ + j*8, &Vs[0][(c*128 + (w<<6))*8]);
    }

    for (int kt = 0; kt < nkt; kt++) {
        const int cur = kt & 1;
        __syncthreads();                       // drains tile-kt DMA (full-iter flight)

        if (kt + 1 < nkt) {                    // prefetch tile kt+1 -> other buffers
            #pragma unroll
            for (int c = 0; c < 4; c++) {
                int idx = c*128 + tid;
                int row = idx >> 3, j = (idx & 7) ^ (row & 7);
                gl_lds16(Km + base + (size_t)((kt+1)*64 + row)*D_ + j*8,
                         &Ks[1-cur][(c*128 + (w<<6))*8]);
            }
            #pragma unroll
            for (int c = 0; c < 4; c++) {
                int idx = c*128 + tid;
                int row = idx >> 3, j = (idx & 7) ^ (row & 7);
                gl_lds16(Vtg + vbase + (size_t)row*S_ + (kt+1)*64 + j*8,
                         &Vs[1-cur][(c*128 + (w<<6))*8]);
            }
        }

        // S^T = K Q^T (log2 domain): sacc[tq][kb] = 32 keys x 32 toks
        // each ak read feeds BOTH q-subtiles (2 MFMAs per ds_read)
        f32x16 sacc[2][2];
        #pragma unroll
        for (int tq = 0; tq < 2; tq++)
            #pragma unroll
            for (int kb = 0; kb < 2; kb++)
                #pragma unroll
                for (int ii = 0; ii < 16; ii++) sacc[tq][kb][ii] = 0.f;
        #pragma unroll
        for (int ks = 0; ks < 4; ks++)
            #pragma unroll
            for (int kb = 0; kb < 2; kb++) {
                int row = kb*32 + l32;
                int c = (ks*2 + hi) ^ (row & 7);
                bf16x8 ak = *(const bf16x8*)&Ks[cur][row*64 + c*8];
                sacc[0][kb] = __builtin_amdgcn_mfma_f32_32x32x16_bf16(ak, aq[0][ks], sacc[0][kb], 0, 0, 0);
                sacc[1][kb] = __builtin_amdgcn_mfma_f32_32x32x16_bf16(ak, aq[1][ks], sacc[1][kb], 0, 0, 0);
            }

        if (kt >= 2*qt) {                      // diagonal tiles: causal mask
            #pragma unroll
            for (int tq = 0; tq < 2; tq++) {
                int tokg = tok0 + tq*32 + l32;
                #pragma unroll
                for (int kb = 0; kb < 2; kb++)
                    #pragma unroll
                    for (int r = 0; r < 16; r++) {
                        int keyg = kt*64 + kb*32 + (r&3) + 8*(r>>2) + 4*hi;
                        if (keyg > tokg) sacc[tq][kb][r] = -INFINITY;
                    }
            }
        }

        // exp2 + in-register pack to PV A-fragments (cvt_pk + permlane32_swap)
        bf16x8 pa[2][4];
        #pragma unroll
        for (int tq = 0; tq < 2; tq++)
            #pragma unroll
            for (int kb = 0; kb < 2; kb++) {
                float pv[16];
                #pragma unroll
                for (int r = 0; r < 16; r++) {
                    pv[r] = EXP2F(sacc[tq][kb][r]);
                    ls[tq][r & 3] += pv[r];
                }
                unsigned wd[8];
                #pragma unroll
                for (int j = 0; j < 8; j++) wd[j] = cvtpk_bf16(pv[2*j], pv[2*j+1]);
                plswap(wd[0], wd[2]); plswap(wd[1], wd[3]);
                plswap(wd[4], wd[6]); plswap(wd[5], wd[7]);
                union { unsigned u[4]; bf16x8 v; } u0, u1;
                u0.u[0]=wd[0]; u0.u[1]=wd[1]; u0.u[2]=wd[2]; u0.u[3]=wd[3];
                u1.u[0]=wd[4]; u1.u[1]=wd[5]; u1.u[2]=wd[6]; u1.u[3]=wd[7];
                pa[tq][2*kb]   = u0.v;
                pa[tq][2*kb+1] = u1.v;
            }

        // O += P V  (V^T staged as [dh][key]; each bv feeds both q-subtiles)
        #pragma unroll
        for (int ks = 0; ks < 4; ks++)
            #pragma unroll
            for (int db = 0; db < 2; db++) {
                int row = db*32 + l32;
                int c = (ks*2 + hi) ^ (row & 7);
                bf16x8 bv = *(const bf16x8*)&Vs[cur][row*64 + c*8];
                oacc[0][db] = __builtin_amdgcn_mfma_f32_32x32x16_bf16(pa[0][ks], bv, oacc[0][db], 0, 0, 0);
                oacc[1][db] = __builtin_amdgcn_mfma_f32_32x32x16_bf16(pa[1][ks], bv, oacc[1][db], 0, 0, 0);
            }
    }

    // normalize + write (per q-subtile)
    #pragma unroll
    for (int tq = 0; tq < 2; tq++) {
        float l = (ls[tq][0] + ls[tq][1]) + (ls[tq][2] + ls[tq][3]);
        l += __shfl_xor(l, 32);
        float inv = 1.f / l;
        #pragma unroll
        for (int r = 0; r < 16; r++) {
            int crow = (r&3) + 8*(r>>2) + 4*hi;
            float invr = __shfl(inv, crow);
            size_t rowo = base + (size_t)(tok0 + tq*32 + crow)*D_;
            #pragma unroll
            for (int db = 0; db < 2; db++)
                Om[rowo + db*32 + l32] = f2bu(oacc[tq][db][r] * invr);
        }
    }
}

// ---------------------------------------------------------------------------
// launch
// ---------------------------------------------------------------------------
extern "C" void kernel_launch(void* const* d_in, const int* in_sizes, int n_in,
                              void* d_out, int out_size, void* d_ws, size_t ws_size,
                              hipStream_t stream)
{
    const unsigned* probe = (const unsigned*)d_in[0];

    unsigned short* u = (unsigned short*)d_ws;
    unsigned short* xc   = u;               size_t o = (size_t)T_*D_;
    unsigned short* wqkv = u + o;           o += (size_t)3*D_*RANK_;
    unsigned short* wOc  = u + o;           o += (size_t)D_*D_;
    unsigned short* Ct   = u + o;           o += (size_t)NZ_*D_;      // 2048 Ct | 64 Rpad | 64 pad
    unsigned short* h3   = u + o;           o += (size_t)3*T_*RANK_;
    unsigned short* QKb  = u + o;           o += (size_t)2*T_*D_;     // Q | K
    unsigned short* Vtg  = u + o;           o += (size_t)T_*D_;
    unsigned short* z    = u + o;           o += (size_t)T_*NZ_;
    unsigned short* attnb= u + o;           o += (size_t)T_*D_;

    unsigned short* Rp = Ct + (size_t)2048*D_;
    unsigned short* Qb = QKb;
    unsigned short* Kb = QKb + (size_t)T_*D_;

    Cvt cv;
    cv.src[0] = d_in[0]; cv.dst[0] = xc;
    cv.src[1] = d_in[3]; cv.dst[1] = Rp;
    cv.src[2] = d_in[4]; cv.dst[2] = Rp + 16384;
    cv.src[3] = d_in[5]; cv.dst[3] = Rp + 32768;
    cv.src[4] = nullptr; cv.dst[4] = Rp + 49152;
    cv.src[5] = d_in[6]; cv.dst[5] = wqkv;
    cv.src[6] = d_in[7]; cv.dst[6] = wqkv + 131072;
    cv.src[7] = d_in[8]; cv.dst[7] = wqkv + 262144;
    cv.src[8] = d_in[9]; cv.dst[8] = wOc;
    cv.C = d_in[2]; cv.Ct = Ct;
    k_inputs<<<512 + 2048, 256, 0, stream>>>(cv, probe);

    k_mfma_gemm<4,0><<<dim3(T_/128, NZ_/128), 256, 0, stream>>>(
        xc, Ct, z, nullptr, T_, NZ_, D_);

    k_hreduce<<<T_/2, 256, 0, stream>>>(z, h3);

    k_qkv2<<<768, 256, 0, stream>>>(h3, wqkv, QKb, Vtg);

    k_flash_mfma<<<dim3(512), 128, 0, stream>>>(Qb, Kb, Vtg, attnb);

    k_mfma_gemm<2,2><<<dim3(T_/64, D_/128), 256, 0, stream>>>(
        attnb, wOc, d_out, probe, T_, D_, D_);
}

// Round 9
// 216.157 us; speedup vs baseline: 1.1708x; 1.1602x over previous
//
#include <hip/hip_runtime.h>
#include <hip/hip_bf16.h>
#include <math.h>

#define B_ 2
#define S_ 2048
#define D_ 1024
#define H_ 16
#define RANK_ 128
#define NC_ 16
#define DH_ 64
#define T_ (B_*S_)
#define NZ_ 2176          // z cols: 2048 z | 64 scores | 64 pad

typedef __attribute__((ext_vector_type(8))) __bf16 bf16x8;
typedef __attribute__((ext_vector_type(8))) unsigned short u16x8;
typedef __attribute__((ext_vector_type(4))) unsigned short u16x4;
typedef __attribute__((ext_vector_type(4))) float f32x4;
typedef __attribute__((ext_vector_type(16))) float f32x16;

#if __has_builtin(__builtin_amdgcn_exp2f)
#define EXP2F(x) __builtin_amdgcn_exp2f(x)
#else
#define EXP2F(x) exp2f(x)
#endif

__device__ __forceinline__ unsigned short f2bu(float f) {
    __hip_bfloat16 h = __float2bfloat16(f);
    unsigned short u; __builtin_memcpy(&u, &h, 2); return u;
}
__device__ __forceinline__ float bu2f(unsigned short u) {
    __hip_bfloat16 h; __builtin_memcpy(&h, &u, 2); return __bfloat162float(h);
}

// async global->LDS 16B/lane; LDS dst = wave-uniform base (+ lane*16 implied)
__device__ __forceinline__ void gl_lds16(const unsigned short* g, unsigned short* l) {
    __builtin_amdgcn_global_load_lds(
        (const __attribute__((address_space(1))) void*)g,
        (__attribute__((address_space(3))) void*)l, 16, 0, 0);
}

// pack two f32 -> one u32 of 2x bf16 (lo -> [15:0])
__device__ __forceinline__ unsigned cvtpk_bf16(float lo, float hi) {
    unsigned r;
    asm("v_cvt_pk_bf16_f32 %0, %1, %2" : "=v"(r) : "v"(lo), "v"(hi));
    return r;
}
// swap hi 32 lanes of a with lo 32 lanes of b (both updated in place)
__device__ __forceinline__ void plswap(unsigned &a, unsigned &b) {
    asm("v_permlane32_swap_b32 %0, %1" : "+v"(a), "+v"(b));
}

__device__ __forceinline__ bool sniff_f32(const unsigned* __restrict__ p) {
    int votes = 0;
    #pragma unroll
    for (int i = 0; i < 64; i++) {
        unsigned e = (p[i] >> 23) & 0xFFu;
        votes += (e >= 0x60u && e <= 0x8Fu) ? 1 : 0;
    }
    return votes >= 32;
}

// ---------------------------------------------------------------------------
// merged input stage: blocks 0..511 = convert+transpose C; rest = flat converts
// (flat converts vectorized x4: all segment offsets are %4==0 so a 4-elem
// granule never spans segments -> f32x4 / 8B loads, 8B stores)
// ---------------------------------------------------------------------------
struct Cvt { const void* src[9]; unsigned short* dst[9]; const void* C; unsigned short* Ct; };

__global__ __launch_bounds__(256) void k_inputs(Cvt cv,
    const unsigned* __restrict__ probe)
{
    bool f32 = sniff_f32(probe);
    if (blockIdx.x < 512) {
        int bid = blockIdx.x;
        int d0 = (bid & 15) * 64, r0 = ((bid >> 4) & 1) * 64, n = bid >> 5;
        __shared__ unsigned short tile[64][65];
        for (int idx = threadIdx.x; idx < 4096; idx += 256) {
            int row = idx >> 6, col = idx & 63;
            size_t si = ((size_t)n*D_ + d0 + row)*RANK_ + r0 + col;
            tile[row][col] = f32 ? f2bu(((const float*)cv.C)[si])
                                 : ((const unsigned short*)cv.C)[si];
        }
        __syncthreads();
        for (int idx = threadIdx.x; idx < 4096; idx += 256) {
            int row = idx >> 6, col = idx & 63;
            cv.Ct[((size_t)(n*RANK_ + r0 + row))*D_ + d0 + col] = tile[col][row];
        }
        return;
    }
    const int offs[9] = {0, 4194304, 4210688, 4227072, 4243456,
                         4259840, 4390912, 4521984, 4653056};
    const int total4 = 5701632 / 4;
    int nconv = gridDim.x - 512;
    int stride = nconv * 256;
    for (int g = (blockIdx.x - 512) * 256 + threadIdx.x; g < total4; g += stride) {
        int i = g * 4;
        int seg = 0;
        #pragma unroll
        for (int s = 1; s < 9; s++) seg += (i >= offs[s]) ? 1 : 0;
        int local = i - offs[seg];
        const void* sp = cv.src[seg];
        u16x4 v = {0, 0, 0, 0};
        if (sp) {
            if (f32) {
                f32x4 x = *(const f32x4*)((const float*)sp + local);
                #pragma unroll
                for (int j = 0; j < 4; j++) v[j] = f2bu(x[j]);
            } else {
                v = *(const u16x4*)((const unsigned short*)sp + local);
            }
        }
        *(u16x4*)(cv.dst[seg] + local) = v;
    }
}

// ---------------------------------------------------------------------------
// MFMA NT GEMM, async-staged. Tile (MT*32)x128, BK=32.
// MODE: 0 = bf16 out; 2 = runtime-sniffed out dtype (fp32 vs bf16)
// ---------------------------------------------------------------------------
template<int MT, int MODE>
__global__ __launch_bounds__(256) void k_mfma_gemm(const unsigned short* __restrict__ A,
    const unsigned short* __restrict__ Bm, void* __restrict__ Cout,
    const unsigned* __restrict__ probe, int M, int N, int K)
{
    bool f32out = false;
    if (MODE == 2) f32out = sniff_f32(probe);
    __shared__ __align__(16) unsigned short As[MT*32*32];
    __shared__ __align__(16) unsigned short Bs[128*32];
    const int tid = threadIdx.x;
    const int wv = tid >> 6, lane = tid & 63;
    const int wm = (wv >> 1) * (MT*16), wn = (wv & 1) * 64;
    const int quad = lane >> 4, l16 = lane & 15;
    const int m0 = blockIdx.x * (MT*32), n0 = blockIdx.y * 128;

    const f32x4 z4 = {0.f, 0.f, 0.f, 0.f};
    f32x4 acc[MT][4];
    #pragma unroll
    for (int i = 0; i < MT; i++)
        #pragma unroll
        for (int j = 0; j < 4; j++) acc[i][j] = z4;

    for (int k0 = 0; k0 < K; k0 += 32) {
        __syncthreads();
        #pragma unroll
        for (int c = 0; c < MT/2; c++) {
            int idx = wv*64 + c*256 + lane;
            gl_lds16(A + (size_t)(m0 + (idx >> 2))*K + k0 + (idx & 3)*8,
                     &As[(wv*64 + c*256)*8]);
        }
        #pragma unroll
        for (int c = 0; c < 2; c++) {
            int idx = wv*64 + c*256 + lane;
            gl_lds16(Bm + (size_t)(n0 + (idx >> 2))*K + k0 + (idx & 3)*8,
                     &Bs[(wv*64 + c*256)*8]);
        }
        __syncthreads();
        bf16x8 af[MT], bfr[4];
        #pragma unroll
        for (int mt = 0; mt < MT; mt++) af[mt]  = *(const bf16x8*)&As[(wm + mt*16 + l16)*32 + quad*8];
        #pragma unroll
        for (int nt = 0; nt < 4; nt++) bfr[nt] = *(const bf16x8*)&Bs[(wn + nt*16 + l16)*32 + quad*8];
        #pragma unroll
        for (int mt = 0; mt < MT; mt++)
            #pragma unroll
            for (int nt = 0; nt < 4; nt++)
                acc[mt][nt] = __builtin_amdgcn_mfma_f32_16x16x32_bf16(af[mt], bfr[nt], acc[mt][nt], 0, 0, 0);
    }
    #pragma unroll
    for (int mt = 0; mt < MT; mt++)
        #pragma unroll
        for (int nt = 0; nt < 4; nt++) {
            int col = n0 + wn + nt*16 + l16;
            #pragma unroll
            for (int r = 0; r < 4; r++) {
                int rowg = m0 + wm + mt*16 + quad*4 + r;
                float v = acc[mt][nt][r];
                if (MODE == 2 && f32out) ((float*)Cout)[(size_t)rowg*N + col] = v;
                else  ((unsigned short*)Cout)[(size_t)rowg*N + col] = f2bu(v);
            }
        }
}

// ---------------------------------------------------------------------------
// merged Q|K + V^T GEMMs (K=128), one launch, 768 blocks.
// ---------------------------------------------------------------------------
__global__ __launch_bounds__(256) void k_qkv2(const unsigned short* __restrict__ h3,
    const unsigned short* __restrict__ wqkv, unsigned short* __restrict__ QKb,
    unsigned short* __restrict__ Vtg)
{
    __shared__ __align__(16) unsigned short As[128*32];
    __shared__ __align__(16) unsigned short Bs[128*32];
    const int tid = threadIdx.x;
    const int wv = tid >> 6, lane = tid & 63;
    const int wm = (wv >> 1) * 64, wn = (wv & 1) * 64;
    const int quad = lane >> 4, l16 = lane & 15;

    const bool vt = (blockIdx.x >= 512);
    int m0, n0;
    const unsigned short *A, *Bm;
    float scale = 1.f;
    if (!vt) {
        int id = blockIdx.x;
        m0 = (id & 31) * 128;                 // tokens
        n0 = (id >> 5) * 128;                 // Q|K cols (0..2047)
        int w = n0 >> 10;
        A  = h3 + (size_t)w * T_ * RANK_ + (size_t)m0 * RANK_;
        Bm = wqkv + (size_t)w * D_ * RANK_ + (size_t)(n0 & 1023) * RANK_;
        if (w == 0) scale = 0.125f * 1.44269504f;
    } else {
        int id = blockIdx.x - 512;
        m0 = (id & 7) * 128;                  // dv rows
        n0 = (id >> 3) * 128;                 // tokens
        A  = wqkv + (size_t)2 * D_ * RANK_ + (size_t)m0 * RANK_;
        Bm = h3 + (size_t)2 * T_ * RANK_ + (size_t)n0 * RANK_;
    }

    const f32x4 z4 = {0.f, 0.f, 0.f, 0.f};
    f32x4 acc[4][4];
    #pragma unroll
    for (int i = 0; i < 4; i++)
        #pragma unroll
        for (int j = 0; j < 4; j++) acc[i][j] = z4;

    for (int k0 = 0; k0 < RANK_; k0 += 32) {
        __syncthreads();
        #pragma unroll
        for (int c = 0; c < 2; c++) {
            int idx = wv*64 + c*256 + lane;
            gl_lds16(A  + (size_t)(idx >> 2)*RANK_ + k0 + (idx & 3)*8,
                     &As[(wv*64 + c*256)*8]);
            gl_lds16(Bm + (size_t)(idx >> 2)*RANK_ + k0 + (idx & 3)*8,
                     &Bs[(wv*64 + c*256)*8]);
        }
        __syncthreads();
        bf16x8 af[4], bfr[4];
        #pragma unroll
        for (int mt = 0; mt < 4; mt++) af[mt]  = *(const bf16x8*)&As[(wm + mt*16 + l16)*32 + quad*8];
        #pragma unroll
        for (int nt = 0; nt < 4; nt++) bfr[nt] = *(const bf16x8*)&Bs[(wn + nt*16 + l16)*32 + quad*8];
        #pragma unroll
        for (int mt = 0; mt < 4; mt++)
            #pragma unroll
            for (int nt = 0; nt < 4; nt++)
                acc[mt][nt] = __builtin_amdgcn_mfma_f32_16x16x32_bf16(af[mt], bfr[nt], acc[mt][nt], 0, 0, 0);
    }
    #pragma unroll
    for (int mt = 0; mt < 4; mt++)
        #pragma unroll
        for (int nt = 0; nt < 4; nt++) {
            #pragma unroll
            for (int r = 0; r < 4; r++) {
                int rowg = m0 + wm + mt*16 + quad*4 + r;
                int col  = n0 + wn + nt*16 + l16;
                float v = acc[mt][nt][r] * scale;
                if (!vt) {
                    QKb[(size_t)(col >> 10)*T_*D_ + (size_t)rowg*D_ + (col & 1023)]
                        = f2bu(v);
                } else {
                    size_t vrow = (size_t)((col >> 11)*H_ + (rowg >> 6))*64 + (rowg & 63);
                    Vtg[vrow*S_ + (col & 2047)] = f2bu(v);
                }
            }
        }
}

// ---------------------------------------------------------------------------
// hreduce + router softmax (scores in z cols 2048..2095)
// ---------------------------------------------------------------------------
__global__ __launch_bounds__(256) void k_hreduce(const unsigned short* __restrict__ z,
    unsigned short* __restrict__ h)
{
    int t0 = blockIdx.x * 2;
    int tg = threadIdx.x >> 7, r = threadIdx.x & 127;
    int t = t0 + tg;
    __shared__ float sc[2][48];
    __shared__ float wl[2][3][16];
    if (threadIdx.x < 96) {
        int tk = threadIdx.x / 48, j = threadIdx.x % 48;
        sc[tk][j] = bu2f(z[(size_t)(t0 + tk)*NZ_ + 2048 + j]);
    }
    __syncthreads();
    if (threadIdx.x < 6) {
        int tk = threadIdx.x / 3, w = threadIdx.x % 3;
        float m = -INFINITY;
        for (int n = 0; n < 16; n++) m = fmaxf(m, sc[tk][w*16 + n]);
        float s = 0.f, e[16];
        for (int n = 0; n < 16; n++) { e[n] = __expf(sc[tk][w*16 + n] - m); s += e[n]; }
        float inv = 1.f / s;
        for (int n = 0; n < 16; n++) wl[tk][w][n] = e[n] * inv;
    }
    __syncthreads();
    const unsigned short* zr = z + (size_t)t * NZ_;
    float acc[3] = {0.f, 0.f, 0.f};
    #pragma unroll
    for (int n = 0; n < NC_; n++) {
        float zv = bu2f(zr[n*RANK_ + r]);
        #pragma unroll
        for (int w = 0; w < 3; w++) acc[w] += wl[tg][w][n] * zv;
    }
    #pragma unroll
    for (int w = 0; w < 3; w++) h[((size_t)w*T_ + t)*RANK_ + r] = f2bu(acc[w]);
}

// ---------------------------------------------------------------------------
// MFMA causal flash attention (R4 proven structure) + T5 setprio.
//   - 32x32x16 swapped QK^T (S^T, token = lane col); lane-local softmax;
//     in-register P->bf16 via v_cvt_pk_bf16_f32 + v_permlane32_swap_b32.
//   - 4 waves x 32 toks = 128-tok q-tile; KVBLK=64; K,V double-buffered via
//     async DMA prefetched one full iteration ahead -> ONE barrier/iter.
//   - flat 512-block grid, complementary CU pairing: block i and i+256 land
//     on the same CU with qt = 15-ts and qt = ts -> constant 34 key-tile
//     visits per CU. i%8 == gr%8 -> XCD-clustered K/V (FETCH 55->12 MB).
//   - NEW (T5): s_setprio(1) around MFMA clusters — 2 independent blocks/CU
//     is m191's regime (+4-7%); pure scheduler hint, zero correctness risk.
// ---------------------------------------------------------------------------
__global__ __launch_bounds__(256, 2) void k_flash_mfma(const unsigned short* __restrict__ Qm,
    const unsigned short* __restrict__ Km, const unsigned short* __restrict__ Vtg,
    unsigned short* __restrict__ Om)
{
    const int i = blockIdx.x;                  // 0..511
    const int half = i >> 8, r_ = i & 255;
    const int gr = r_ & 31, ts = r_ >> 5;      // gr = (b,h) group; ts = 0..7
    const int qt = half ? ts : (15 - ts);      // complementary halves
    const int hh = gr & 15, b = gr >> 4;

    __shared__ __align__(16) unsigned short Ks[2][64*64];  // [key][dh], xor-swz
    __shared__ __align__(16) unsigned short Vs[2][64*64];  // [dh][key], xor-swz
    const int tid = threadIdx.x;
    const int w = tid >> 6, lane = tid & 63;
    const int l32 = lane & 31, hi = lane >> 5;
    const size_t base  = ((size_t)b * S_) * D_ + (size_t)hh * DH_;
    const size_t vbase = (size_t)((b*H_ + hh) * 64) * S_;
    const int tokg = qt*128 + w*32 + l32;      // this lane's token (B-operand col)

    // Q fragments: B-operand, 4 dh-chunks of 16 (lane supplies k = hi*8..+8)
    bf16x8 aq[4];
    #pragma unroll
    for (int ks = 0; ks < 4; ks++)
        aq[ks] = *(const bf16x8*)(Qm + base + (size_t)tokg*D_ + ks*16 + hi*8);

    f32x16 oacc[2];
    #pragma unroll
    for (int db = 0; db < 2; db++)
        #pragma unroll
        for (int ii = 0; ii < 16; ii++) oacc[db][ii] = 0.f;
    float lsum = 0.f;

    const int nkt = 2*(qt + 1);                // 64-key tiles up to the diagonal

    // prefetch tile 0 -> buf 0  (64 rows x 8 chunks, 2 chunks/thread each)
    #pragma unroll
    for (int c = 0; c < 2; c++) {
        int idx = c*256 + tid;
        int row = idx >> 3, j = (idx & 7) ^ (row & 7);
        gl_lds16(Km + base + (size_t)row*D_ + j*8, &Ks[0][(c*256 + (w<<6))*8]);
    }
    #pragma unroll
    for (int c = 0; c < 2; c++) {
        int idx = c*256 + tid;
        int row = idx >> 3, j = (idx & 7) ^ (row & 7);
        gl_lds16(Vtg + vbase + (size_t)row*S_ + j*8, &Vs[0][(c*256 + (w<<6))*8]);
    }

    for (int kt = 0; kt < nkt; kt++) {
        const int cur = kt & 1;
        __syncthreads();                       // drains tile-kt DMA (full-iter flight)

        if (kt + 1 < nkt) {                    // prefetch tile kt+1 -> other buffers
            #pragma unroll
            for (int c = 0; c < 2; c++) {
                int idx = c*256 + tid;
                int row = idx >> 3, j = (idx & 7) ^ (row & 7);
                gl_lds16(Km + base + (size_t)((kt+1)*64 + row)*D_ + j*8,
                         &Ks[1-cur][(c*256 + (w<<6))*8]);
            }
            #pragma unroll
            for (int c = 0; c < 2; c++) {
                int idx = c*256 + tid;
                int row = idx >> 3, j = (idx & 7) ^ (row & 7);
                gl_lds16(Vtg + vbase + (size_t)row*S_ + (kt+1)*64 + j*8,
                         &Vs[1-cur][(c*256 + (w<<6))*8]);
            }
        }

        // S^T = K Q^T (log2 domain): sacc[kb] = 32 keys x 32 toks, tok = lane col
        f32x16 sacc[2];
        #pragma unroll
        for (int kb = 0; kb < 2; kb++)
            #pragma unroll
            for (int ii = 0; ii < 16; ii++) sacc[kb][ii] = 0.f;
        __builtin_amdgcn_s_setprio(1);
        #pragma unroll
        for (int ks = 0; ks < 4; ks++)
            #pragma unroll
            for (int kb = 0; kb < 2; kb++) {
                int row = kb*32 + l32;
                int c = (ks*2 + hi) ^ (row & 7);
                bf16x8 ak = *(const bf16x8*)&Ks[cur][row*64 + c*8];
                sacc[kb] = __builtin_amdgcn_mfma_f32_32x32x16_bf16(ak, aq[ks], sacc[kb], 0, 0, 0);
            }
        __builtin_amdgcn_s_setprio(0);

        if (kt >= 2*qt) {                      // diagonal tiles: causal mask
            #pragma unroll
            for (int kb = 0; kb < 2; kb++)
                #pragma unroll
                for (int r = 0; r < 16; r++) {
                    int keyg = kt*64 + kb*32 + (r&3) + 8*(r>>2) + 4*hi;
                    if (keyg > tokg) sacc[kb][r] = -INFINITY;
                }
        }

        // exp2 + in-register pack to PV A-fragments (cvt_pk + permlane32_swap)
        bf16x8 pa[4];
        #pragma unroll
        for (int kb = 0; kb < 2; kb++) {
            float pv[16];
            #pragma unroll
            for (int r = 0; r < 16; r++) {
                pv[r] = EXP2F(sacc[kb][r]);
                lsum += pv[r];
            }
            unsigned wd[8];
            #pragma unroll
            for (int j = 0; j < 8; j++) wd[j] = cvtpk_bf16(pv[2*j], pv[2*j+1]);
            plswap(wd[0], wd[2]); plswap(wd[1], wd[3]);
            plswap(wd[4], wd[6]); plswap(wd[5], wd[7]);
            union { unsigned u[4]; bf16x8 v; } u0, u1;
            u0.u[0]=wd[0]; u0.u[1]=wd[1]; u0.u[2]=wd[2]; u0.u[3]=wd[3];
            u1.u[0]=wd[4]; u1.u[1]=wd[5]; u1.u[2]=wd[6]; u1.u[3]=wd[7];
            pa[2*kb]   = u0.v;
            pa[2*kb+1] = u1.v;
        }

        // O += P V  (V^T staged as [dh][key]; B-operand rows = dh)
        __builtin_amdgcn_s_setprio(1);
        #pragma unroll
        for (int ks = 0; ks < 4; ks++)
            #pragma unroll
            for (int db = 0; db < 2; db++) {
                int row = db*32 + l32;
                int c = (ks*2 + hi) ^ (row & 7);
                bf16x8 bv = *(const bf16x8*)&Vs[cur][row*64 + c*8];
                oacc[db] = __builtin_amdgcn_mfma_f32_32x32x16_bf16(pa[ks], bv, oacc[db], 0, 0, 0);
            }
        __builtin_amdgcn_s_setprio(0);
    }

    // normalize + write: lane l<32 holds lsum for token l; O rows are reg-mapped
    float l = lsum + __shfl_xor(lsum, 32);
    float inv = 1.f / l;
    #pragma unroll
    for (int r = 0; r < 16; r++) {
        int crow = (r&3) + 8*(r>>2) + 4*hi;
        float invr = __shfl(inv, crow);
        size_t rowo = base + (size_t)(qt*128 + w*32 + crow)*D_;
        #pragma unroll
        for (int db = 0; db < 2; db++)
            Om[rowo + db*32 + l32] = f2bu(oacc[db][r] * invr);
    }
}

// ---------------------------------------------------------------------------
// launch
// ---------------------------------------------------------------------------
extern "C" void kernel_launch(void* const* d_in, const int* in_sizes, int n_in,
                              void* d_out, int out_size, void* d_ws, size_t ws_size,
                              hipStream_t stream)
{
    const unsigned* probe = (const unsigned*)d_in[0];

    unsigned short* u = (unsigned short*)d_ws;
    unsigned short* xc   = u;               size_t o = (size_t)T_*D_;
    unsigned short* wqkv = u + o;           o += (size_t)3*D_*RANK_;
    unsigned short* wOc  = u + o;           o += (size_t)D_*D_;
    unsigned short* Ct   = u + o;           o += (size_t)NZ_*D_;      // 2048 Ct | 64 Rpad | 64 pad
    unsigned short* h3   = u + o;           o += (size_t)3*T_*RANK_;
    unsigned short* QKb  = u + o;           o += (size_t)2*T_*D_;     // Q | K
    unsigned short* Vtg  = u + o;           o += (size_t)T_*D_;
    unsigned short* z    = u + o;           o += (size_t)T_*NZ_;
    unsigned short* attnb= u + o;           o += (size_t)T_*D_;

    unsigned short* Rp = Ct + (size_t)2048*D_;
    unsigned short* Qb = QKb;
    unsigned short* Kb = QKb + (size_t)T_*D_;

    Cvt cv;
    cv.src[0] = d_in[0]; cv.dst[0] = xc;
    cv.src[1] = d_in[3]; cv.dst[1] = Rp;
    cv.src[2] = d_in[4]; cv.dst[2] = Rp + 16384;
    cv.src[3] = d_in[5]; cv.dst[3] = Rp + 32768;
    cv.src[4] = nullptr; cv.dst[4] = Rp + 49152;
    cv.src[5] = d_in[6]; cv.dst[5] = wqkv;
    cv.src[6] = d_in[7]; cv.dst[6] = wqkv + 131072;
    cv.src[7] = d_in[8]; cv.dst[7] = wqkv + 262144;
    cv.src[8] = d_in[9]; cv.dst[8] = wOc;
    cv.C = d_in[2]; cv.Ct = Ct;
    k_inputs<<<512 + 1024, 256, 0, stream>>>(cv, probe);

    k_mfma_gemm<4,0><<<dim3(T_/128, NZ_/128), 256, 0, stream>>>(
        xc, Ct, z, nullptr, T_, NZ_, D_);

    k_hreduce<<<T_/2, 256, 0, stream>>>(z, h3);

    k_qkv2<<<768, 256, 0, stream>>>(h3, wqkv, QKb, Vtg);

    k_flash_mfma<<<dim3(512), 256, 0, stream>>>(Qb, Kb, Vtg, attnb);

    k_mfma_gemm<2,2><<<dim3(T_/64, D_/128), 256, 0, stream>>>(
        attnb, wOc, d_out, probe, T_, D_, D_);
}

// Round 10
// 215.162 us; speedup vs baseline: 1.1763x; 1.0046x over previous
//
#include <hip/hip_runtime.h>
#include <hip/hip_bf16.h>
#include <math.h>

#define B_ 2
#define S_ 2048
#define D_ 1024
#define H_ 16
#define RANK_ 128
#define NC_ 16
#define DH_ 64
#define T_ (B_*S_)
#define NZ_ 2176          // z cols: 2048 z | 64 scores | 64 pad

typedef __attribute__((ext_vector_type(8))) __bf16 bf16x8;
typedef __attribute__((ext_vector_type(8))) unsigned short u16x8;
typedef __attribute__((ext_vector_type(4))) unsigned short u16x4;
typedef __attribute__((ext_vector_type(4))) float f32x4;
typedef __attribute__((ext_vector_type(16))) float f32x16;

#if __has_builtin(__builtin_amdgcn_exp2f)
#define EXP2F(x) __builtin_amdgcn_exp2f(x)
#else
#define EXP2F(x) exp2f(x)
#endif

__device__ __forceinline__ unsigned short f2bu(float f) {
    __hip_bfloat16 h = __float2bfloat16(f);
    unsigned short u; __builtin_memcpy(&u, &h, 2); return u;
}
__device__ __forceinline__ float bu2f(unsigned short u) {
    __hip_bfloat16 h; __builtin_memcpy(&h, &u, 2); return __bfloat162float(h);
}

// async global->LDS 16B/lane; LDS dst = wave-uniform base (+ lane*16 implied)
__device__ __forceinline__ void gl_lds16(const unsigned short* g, unsigned short* l) {
    __builtin_amdgcn_global_load_lds(
        (const __attribute__((address_space(1))) void*)g,
        (__attribute__((address_space(3))) void*)l, 16, 0, 0);
}

// pack two f32 -> one u32 of 2x bf16 (lo -> [15:0])
__device__ __forceinline__ unsigned cvtpk_bf16(float lo, float hi) {
    unsigned r;
    asm("v_cvt_pk_bf16_f32 %0, %1, %2" : "=v"(r) : "v"(lo), "v"(hi));
    return r;
}
// swap hi 32 lanes of a with lo 32 lanes of b (both updated in place)
__device__ __forceinline__ void plswap(unsigned &a, unsigned &b) {
    asm("v_permlane32_swap_b32 %0, %1" : "+v"(a), "+v"(b));
}

__device__ __forceinline__ bool sniff_f32(const unsigned* __restrict__ p) {
    int votes = 0;
    #pragma unroll
    for (int i = 0; i < 64; i++) {
        unsigned e = (p[i] >> 23) & 0xFFu;
        votes += (e >= 0x60u && e <= 0x8Fu) ? 1 : 0;
    }
    return votes >= 32;
}

// ---------------------------------------------------------------------------
// merged input stage: blocks 0..511 = convert+transpose C; rest = flat converts
// (flat converts vectorized x4: all segment offsets are %4==0 so a 4-elem
// granule never spans segments -> f32x4 / 8B loads, 8B stores)
// ---------------------------------------------------------------------------
struct Cvt { const void* src[9]; unsigned short* dst[9]; const void* C; unsigned short* Ct; };

__global__ __launch_bounds__(256) void k_inputs(Cvt cv,
    const unsigned* __restrict__ probe)
{
    bool f32 = sniff_f32(probe);
    if (blockIdx.x < 512) {
        int bid = blockIdx.x;
        int d0 = (bid & 15) * 64, r0 = ((bid >> 4) & 1) * 64, n = bid >> 5;
        __shared__ unsigned short tile[64][65];
        for (int idx = threadIdx.x; idx < 4096; idx += 256) {
            int row = idx >> 6, col = idx & 63;
            size_t si = ((size_t)n*D_ + d0 + row)*RANK_ + r0 + col;
            tile[row][col] = f32 ? f2bu(((const float*)cv.C)[si])
                                 : ((const unsigned short*)cv.C)[si];
        }
        __syncthreads();
        for (int idx = threadIdx.x; idx < 4096; idx += 256) {
            int row = idx >> 6, col = idx & 63;
            cv.Ct[((size_t)(n*RANK_ + r0 + row))*D_ + d0 + col] = tile[col][row];
        }
        return;
    }
    const int offs[9] = {0, 4194304, 4210688, 4227072, 4243456,
                         4259840, 4390912, 4521984, 4653056};
    const int total4 = 5701632 / 4;
    int nconv = gridDim.x - 512;
    int stride = nconv * 256;
    for (int g = (blockIdx.x - 512) * 256 + threadIdx.x; g < total4; g += stride) {
        int i = g * 4;
        int seg = 0;
        #pragma unroll
        for (int s = 1; s < 9; s++) seg += (i >= offs[s]) ? 1 : 0;
        int local = i - offs[seg];
        const void* sp = cv.src[seg];
        u16x4 v = {0, 0, 0, 0};
        if (sp) {
            if (f32) {
                f32x4 x = *(const f32x4*)((const float*)sp + local);
                #pragma unroll
                for (int j = 0; j < 4; j++) v[j] = f2bu(x[j]);
            } else {
                v = *(const u16x4*)((const unsigned short*)sp + local);
            }
        }
        *(u16x4*)(cv.dst[seg] + local) = v;
    }
}

// ---------------------------------------------------------------------------
// MFMA NT GEMM, async-staged. Tile (MT*32)x128, BK=32.
// MODE: 0 = bf16 out; 2 = runtime-sniffed out dtype (fp32 vs bf16)
// ---------------------------------------------------------------------------
template<int MT, int MODE>
__global__ __launch_bounds__(256) void k_mfma_gemm(const unsigned short* __restrict__ A,
    const unsigned short* __restrict__ Bm, void* __restrict__ Cout,
    const unsigned* __restrict__ probe, int M, int N, int K)
{
    bool f32out = false;
    if (MODE == 2) f32out = sniff_f32(probe);
    __shared__ __align__(16) unsigned short As[MT*32*32];
    __shared__ __align__(16) unsigned short Bs[128*32];
    const int tid = threadIdx.x;
    const int wv = tid >> 6, lane = tid & 63;
    const int wm = (wv >> 1) * (MT*16), wn = (wv & 1) * 64;
    const int quad = lane >> 4, l16 = lane & 15;
    const int m0 = blockIdx.x * (MT*32), n0 = blockIdx.y * 128;

    const f32x4 z4 = {0.f, 0.f, 0.f, 0.f};
    f32x4 acc[MT][4];
    #pragma unroll
    for (int i = 0; i < MT; i++)
        #pragma unroll
        for (int j = 0; j < 4; j++) acc[i][j] = z4;

    for (int k0 = 0; k0 < K; k0 += 32) {
        __syncthreads();
        #pragma unroll
        for (int c = 0; c < MT/2; c++) {
            int idx = wv*64 + c*256 + lane;
            gl_lds16(A + (size_t)(m0 + (idx >> 2))*K + k0 + (idx & 3)*8,
                     &As[(wv*64 + c*256)*8]);
        }
        #pragma unroll
        for (int c = 0; c < 2; c++) {
            int idx = wv*64 + c*256 + lane;
            gl_lds16(Bm + (size_t)(n0 + (idx >> 2))*K + k0 + (idx & 3)*8,
                     &Bs[(wv*64 + c*256)*8]);
        }
        __syncthreads();
        bf16x8 af[MT], bfr[4];
        #pragma unroll
        for (int mt = 0; mt < MT; mt++) af[mt]  = *(const bf16x8*)&As[(wm + mt*16 + l16)*32 + quad*8];
        #pragma unroll
        for (int nt = 0; nt < 4; nt++) bfr[nt] = *(const bf16x8*)&Bs[(wn + nt*16 + l16)*32 + quad*8];
        #pragma unroll
        for (int mt = 0; mt < MT; mt++)
            #pragma unroll
            for (int nt = 0; nt < 4; nt++)
                acc[mt][nt] = __builtin_amdgcn_mfma_f32_16x16x32_bf16(af[mt], bfr[nt], acc[mt][nt], 0, 0, 0);
    }
    #pragma unroll
    for (int mt = 0; mt < MT; mt++)
        #pragma unroll
        for (int nt = 0; nt < 4; nt++) {
            int col = n0 + wn + nt*16 + l16;
            #pragma unroll
            for (int r = 0; r < 4; r++) {
                int rowg = m0 + wm + mt*16 + quad*4 + r;
                float v = acc[mt][nt][r];
                if (MODE == 2 && f32out) ((float*)Cout)[(size_t)rowg*N + col] = v;
                else  ((unsigned short*)Cout)[(size_t)rowg*N + col] = f2bu(v);
            }
        }
}

// ---------------------------------------------------------------------------
// merged Q|K + V^T GEMMs (K=128), one launch, 768 blocks.
// ---------------------------------------------------------------------------
__global__ __launch_bounds__(256) void k_qkv2(const unsigned short* __restrict__ h3,
    const unsigned short* __restrict__ wqkv, unsigned short* __restrict__ QKb,
    unsigned short* __restrict__ Vtg)
{
    __shared__ __align__(16) unsigned short As[128*32];
    __shared__ __align__(16) unsigned short Bs[128*32];
    const int tid = threadIdx.x;
    const int wv = tid >> 6, lane = tid & 63;
    const int wm = (wv >> 1) * 64, wn = (wv & 1) * 64;
    const int quad = lane >> 4, l16 = lane & 15;

    const bool vt = (blockIdx.x >= 512);
    int m0, n0;
    const unsigned short *A, *Bm;
    float scale = 1.f;
    if (!vt) {
        int id = blockIdx.x;
        m0 = (id & 31) * 128;                 // tokens
        n0 = (id >> 5) * 128;                 // Q|K cols (0..2047)
        int w = n0 >> 10;
        A  = h3 + (size_t)w * T_ * RANK_ + (size_t)m0 * RANK_;
        Bm = wqkv + (size_t)w * D_ * RANK_ + (size_t)(n0 & 1023) * RANK_;
        if (w == 0) scale = 0.125f * 1.44269504f;
    } else {
        int id = blockIdx.x - 512;
        m0 = (id & 7) * 128;                  // dv rows
        n0 = (id >> 3) * 128;                 // tokens
        A  = wqkv + (size_t)2 * D_ * RANK_ + (size_t)m0 * RANK_;
        Bm = h3 + (size_t)2 * T_ * RANK_ + (size_t)n0 * RANK_;
    }

    const f32x4 z4 = {0.f, 0.f, 0.f, 0.f};
    f32x4 acc[4][4];
    #pragma unroll
    for (int i = 0; i < 4; i++)
        #pragma unroll
        for (int j = 0; j < 4; j++) acc[i][j] = z4;

    for (int k0 = 0; k0 < RANK_; k0 += 32) {
        __syncthreads();
        #pragma unroll
        for (int c = 0; c < 2; c++) {
            int idx = wv*64 + c*256 + lane;
            gl_lds16(A  + (size_t)(idx >> 2)*RANK_ + k0 + (idx & 3)*8,
                     &As[(wv*64 + c*256)*8]);
            gl_lds16(Bm + (size_t)(idx >> 2)*RANK_ + k0 + (idx & 3)*8,
                     &Bs[(wv*64 + c*256)*8]);
        }
        __syncthreads();
        bf16x8 af[4], bfr[4];
        #pragma unroll
        for (int mt = 0; mt < 4; mt++) af[mt]  = *(const bf16x8*)&As[(wm + mt*16 + l16)*32 + quad*8];
        #pragma unroll
        for (int nt = 0; nt < 4; nt++) bfr[nt] = *(const bf16x8*)&Bs[(wn + nt*16 + l16)*32 + quad*8];
        #pragma unroll
        for (int mt = 0; mt < 4; mt++)
            #pragma unroll
            for (int nt = 0; nt < 4; nt++)
                acc[mt][nt] = __builtin_amdgcn_mfma_f32_16x16x32_bf16(af[mt], bfr[nt], acc[mt][nt], 0, 0, 0);
    }
    #pragma unroll
    for (int mt = 0; mt < 4; mt++)
        #pragma unroll
        for (int nt = 0; nt < 4; nt++) {
            #pragma unroll
            for (int r = 0; r < 4; r++) {
                int rowg = m0 + wm + mt*16 + quad*4 + r;
                int col  = n0 + wn + nt*16 + l16;
                float v = acc[mt][nt][r] * scale;
                if (!vt) {
                    QKb[(size_t)(col >> 10)*T_*D_ + (size_t)rowg*D_ + (col & 1023)]
                        = f2bu(v);
                } else {
                    size_t vrow = (size_t)((col >> 11)*H_ + (rowg >> 6))*64 + (rowg & 63);
                    Vtg[vrow*S_ + (col & 2047)] = f2bu(v);
                }
            }
        }
}

// ---------------------------------------------------------------------------
// hreduce + router softmax (scores in z cols 2048..2095)
// ---------------------------------------------------------------------------
__global__ __launch_bounds__(256) void k_hreduce(const unsigned short* __restrict__ z,
    unsigned short* __restrict__ h)
{
    int t0 = blockIdx.x * 2;
    int tg = threadIdx.x >> 7, r = threadIdx.x & 127;
    int t = t0 + tg;
    __shared__ float sc[2][48];
    __shared__ float wl[2][3][16];
    if (threadIdx.x < 96) {
        int tk = threadIdx.x / 48, j = threadIdx.x % 48;
        sc[tk][j] = bu2f(z[(size_t)(t0 + tk)*NZ_ + 2048 + j]);
    }
    __syncthreads();
    if (threadIdx.x < 6) {
        int tk = threadIdx.x / 3, w = threadIdx.x % 3;
        float m = -INFINITY;
        for (int n = 0; n < 16; n++) m = fmaxf(m, sc[tk][w*16 + n]);
        float s = 0.f, e[16];
        for (int n = 0; n < 16; n++) { e[n] = __expf(sc[tk][w*16 + n] - m); s += e[n]; }
        float inv = 1.f / s;
        for (int n = 0; n < 16; n++) wl[tk][w][n] = e[n] * inv;
    }
    __syncthreads();
    const unsigned short* zr = z + (size_t)t * NZ_;
    float acc[3] = {0.f, 0.f, 0.f};
    #pragma unroll
    for (int n = 0; n < NC_; n++) {
        float zv = bu2f(zr[n*RANK_ + r]);
        #pragma unroll
        for (int w = 0; w < 3; w++) acc[w] += wl[tg][w][n] * zv;
    }
    #pragma unroll
    for (int w = 0; w < 3; w++) h[((size_t)w*T_ + t)*RANK_ + r] = f2bu(acc[w]);
}

// ---------------------------------------------------------------------------
// MFMA causal flash attention — R4 structure + T15 cross-iteration skew.
//   - 32x32x16 swapped QK^T (S^T, token = lane col); lane-local softmax;
//     in-register P->bf16 via v_cvt_pk_bf16_f32 + v_permlane32_swap_b32.
//   - 4 waves x 32 toks = 128-tok q-tile; KVBLK=64.
//   - NEW: 3-deep LDS ring (48 KiB), stage kt+2 each iter. At iteration kt
//     both tiles kt and kt+1 are barrier-drained, so the body computes
//     QK(kt+1) FIRST, then softmax(kt) on the PREVIOUS tile's scores:
//     exp2 never waits on just-issued MFMAs, and the QK MFMA cluster
//     retires under softmax VALU (T15 att[2] pattern, m214v36 +8-11%).
//   - ONE barrier/iter (drains this iter's stage at next iter top).
//   - Complementary CU pairing kept: block i and i+256 share a CU with
//     qt = 15-ts / ts -> constant 34 visits/CU; i%8==gr%8 XCD-clusters K/V.
//   - No setprio (R9 A/B: 43.9 vs R4 41.1 -> negative in lockstep, dropped).
// ---------------------------------------------------------------------------
__global__ __launch_bounds__(256, 2) void k_flash_mfma(const unsigned short* __restrict__ Qm,
    const unsigned short* __restrict__ Km, const unsigned short* __restrict__ Vtg,
    unsigned short* __restrict__ Om)
{
    const int i = blockIdx.x;                  // 0..511
    const int half = i >> 8, r_ = i & 255;
    const int gr = r_ & 31, ts = r_ >> 5;      // gr = (b,h) group; ts = 0..7
    const int qt = half ? ts : (15 - ts);      // complementary halves
    const int hh = gr & 15, b = gr >> 4;

    __shared__ __align__(16) unsigned short Ks[3][64*64];  // [key][dh], xor-swz
    __shared__ __align__(16) unsigned short Vs[3][64*64];  // [dh][key], xor-swz
    const int tid = threadIdx.x;
    const int w = tid >> 6, lane = tid & 63;
    const int l32 = lane & 31, hi = lane >> 5;
    const size_t base  = ((size_t)b * S_) * D_ + (size_t)hh * DH_;
    const size_t vbase = (size_t)((b*H_ + hh) * 64) * S_;
    const int tokg = qt*128 + w*32 + l32;      // this lane's token (B-operand col)

    // Q fragments: B-operand, 4 dh-chunks of 16 (lane supplies k = hi*8..+8)
    bf16x8 aq[4];
    #pragma unroll
    for (int ks = 0; ks < 4; ks++)
        aq[ks] = *(const bf16x8*)(Qm + base + (size_t)tokg*D_ + ks*16 + hi*8);

    f32x16 oacc[2];
    #pragma unroll
    for (int db = 0; db < 2; db++)
        #pragma unroll
        for (int ii = 0; ii < 16; ii++) oacc[db][ii] = 0.f;
    float lsum = 0.f;

    const int nkt = 2*(qt + 1);                // 64-key tiles up to the diagonal

    auto STAGE = [&](int kt_, int bf_) {
        #pragma unroll
        for (int c = 0; c < 2; c++) {
            int idx = c*256 + tid;
            int row = idx >> 3, j = (idx & 7) ^ (row & 7);
            gl_lds16(Km + base + (size_t)(kt_*64 + row)*D_ + j*8,
                     &Ks[bf_][(c*256 + (w<<6))*8]);
        }
        #pragma unroll
        for (int c = 0; c < 2; c++) {
            int idx = c*256 + tid;
            int row = idx >> 3, j = (idx & 7) ^ (row & 7);
            gl_lds16(Vtg + vbase + (size_t)row*S_ + kt_*64 + j*8,
                     &Vs[bf_][(c*256 + (w<<6))*8]);
        }
    };

    // S^T = K Q^T (log2 domain) for tile kt_ -> (s0,s1) = 2x (32 keys x 32 toks)
    auto QKT = [&](int bf_, f32x16& s0, f32x16& s1) {
        #pragma unroll
        for (int ii = 0; ii < 16; ii++) { s0[ii] = 0.f; s1[ii] = 0.f; }
        const unsigned short* Kp = Ks[bf_];
        #pragma unroll
        for (int ks = 0; ks < 4; ks++) {
            int c0 = (ks*2 + hi) ^ (l32 & 7);
            bf16x8 ak0 = *(const bf16x8*)&Kp[l32*64 + c0*8];
            s0 = __builtin_amdgcn_mfma_f32_32x32x16_bf16(ak0, aq[ks], s0, 0, 0, 0);
            int row1 = 32 + l32;
            int c1 = (ks*2 + hi) ^ (row1 & 7);
            bf16x8 ak1 = *(const bf16x8*)&Kp[row1*64 + c1*8];
            s1 = __builtin_amdgcn_mfma_f32_32x32x16_bf16(ak1, aq[ks], s1, 0, 0, 0);
        }
    };

    STAGE(0, 0);
    STAGE(1, 1);                               // nkt >= 2 always
    __syncthreads();                           // tiles 0 and 1 resident

    f32x16 sA0, sA1, sB0, sB1;
    QKT(0, sA0, sA1);

    for (int kt = 0; kt < nkt; kt++) {
        const int cur = kt % 3;
        if (kt + 2 < nkt) STAGE(kt + 2, (kt + 2) % 3);  // overwrites buf (kt-1)%3: readers done pre-barrier
        if (kt + 1 < nkt) QKT((kt + 1) % 3, sB0, sB1);  // tile kt+1 drained by last barrier

        if (kt >= 2*qt) {                      // diagonal tiles: causal mask (on sA)
            #pragma unroll
            for (int r = 0; r < 16; r++) {
                int crow = (r&3) + 8*(r>>2) + 4*hi;
                int keyg0 = kt*64 + crow;
                int keyg1 = kt*64 + 32 + crow;
                if (keyg0 > tokg) sA0[r] = -INFINITY;
                if (keyg1 > tokg) sA1[r] = -INFINITY;
            }
        }

        // exp2 + in-register pack to PV A-fragments (cvt_pk + permlane32_swap)
        bf16x8 pa[4];
        #pragma unroll
        for (int kb = 0; kb < 2; kb++) {
            float pv[16];
            #pragma unroll
            for (int r = 0; r < 16; r++) {
                pv[r] = EXP2F(kb ? sA1[r] : sA0[r]);
                lsum += pv[r];
            }
            unsigned wd[8];
            #pragma unroll
            for (int j = 0; j < 8; j++) wd[j] = cvtpk_bf16(pv[2*j], pv[2*j+1]);
            plswap(wd[0], wd[2]); plswap(wd[1], wd[3]);
            plswap(wd[4], wd[6]); plswap(wd[5], wd[7]);
            union { unsigned u[4]; bf16x8 v; } u0, u1;
            u0.u[0]=wd[0]; u0.u[1]=wd[1]; u0.u[2]=wd[2]; u0.u[3]=wd[3];
            u1.u[0]=wd[4]; u1.u[1]=wd[5]; u1.u[2]=wd[6]; u1.u[3]=wd[7];
            pa[2*kb]   = u0.v;
            pa[2*kb+1] = u1.v;
        }

        // O += P V  (V^T staged as [dh][key]; B-operand rows = dh)
        #pragma unroll
        for (int ks = 0; ks < 4; ks++)
            #pragma unroll
            for (int db = 0; db < 2; db++) {
                int row = db*32 + l32;
                int c = (ks*2 + hi) ^ (row & 7);
                bf16x8 bv = *(const bf16x8*)&Vs[cur][row*64 + c*8];
                oacc[db] = __builtin_amdgcn_mfma_f32_32x32x16_bf16(pa[ks], bv, oacc[db], 0, 0, 0);
            }

        if (kt + 1 < nkt) { sA0 = sB0; sA1 = sB1; }
        __syncthreads();                       // drains this iter's STAGE; LDS reads done
    }

    // normalize + write: lane l<32 holds lsum for token l; O rows are reg-mapped
    float l = lsum + __shfl_xor(lsum, 32);
    float inv = 1.f / l;
    #pragma unroll
    for (int r = 0; r < 16; r++) {
        int crow = (r&3) + 8*(r>>2) + 4*hi;
        float invr = __shfl(inv, crow);
        size_t rowo = base + (size_t)(qt*128 + w*32 + crow)*D_;
        #pragma unroll
        for (int db = 0; db < 2; db++)
            Om[rowo + db*32 + l32] = f2bu(oacc[db][r] * invr);
    }
}

// ---------------------------------------------------------------------------
// launch
// ---------------------------------------------------------------------------
extern "C" void kernel_launch(void* const* d_in, const int* in_sizes, int n_in,
                              void* d_out, int out_size, void* d_ws, size_t ws_size,
                              hipStream_t stream)
{
    const unsigned* probe = (const unsigned*)d_in[0];

    unsigned short* u = (unsigned short*)d_ws;
    unsigned short* xc   = u;               size_t o = (size_t)T_*D_;
    unsigned short* wqkv = u + o;           o += (size_t)3*D_*RANK_;
    unsigned short* wOc  = u + o;           o += (size_t)D_*D_;
    unsigned short* Ct   = u + o;           o += (size_t)NZ_*D_;      // 2048 Ct | 64 Rpad | 64 pad
    unsigned short* h3   = u + o;           o += (size_t)3*T_*RANK_;
    unsigned short* QKb  = u + o;           o += (size_t)2*T_*D_;     // Q | K
    unsigned short* Vtg  = u + o;           o += (size_t)T_*D_;
    unsigned short* z    = u + o;           o += (size_t)T_*NZ_;
    unsigned short* attnb= u + o;           o += (size_t)T_*D_;

    unsigned short* Rp = Ct + (size_t)2048*D_;
    unsigned short* Qb = QKb;
    unsigned short* Kb = QKb + (size_t)T_*D_;

    Cvt cv;
    cv.src[0] = d_in[0]; cv.dst[0] = xc;
    cv.src[1] = d_in[3]; cv.dst[1] = Rp;
    cv.src[2] = d_in[4]; cv.dst[2] = Rp + 16384;
    cv.src[3] = d_in[5]; cv.dst[3] = Rp + 32768;
    cv.src[4] = nullptr; cv.dst[4] = Rp + 49152;
    cv.src[5] = d_in[6]; cv.dst[5] = wqkv;
    cv.src[6] = d_in[7]; cv.dst[6] = wqkv + 131072;
    cv.src[7] = d_in[8]; cv.dst[7] = wqkv + 262144;
    cv.src[8] = d_in[9]; cv.dst[8] = wOc;
    cv.C = d_in[2]; cv.Ct = Ct;
    k_inputs<<<512 + 1024, 256, 0, stream>>>(cv, probe);

    k_mfma_gemm<4,0><<<dim3(T_/128, NZ_/128), 256, 0, stream>>>(
        xc, Ct, z, nullptr, T_, NZ_, D_);

    k_hreduce<<<T_/2, 256, 0, stream>>>(z, h3);

    k_qkv2<<<768, 256, 0, stream>>>(h3, wqkv, QKb, Vtg);

    k_flash_mfma<<<dim3(512), 256, 0, stream>>>(Qb, Kb, Vtg, attnb);

    k_mfma_gemm<2,2><<<dim3(T_/64, D_/128), 256, 0, stream>>>(
        attnb, wOc, d_out, probe, T_, D_, D_);
}